// Round 3
// baseline (2661.081 us; speedup 1.0000x reference)
//
#include <hip/hip_runtime.h>
#include <math.h>

typedef unsigned int u32;
typedef unsigned long long u64;

#define HH 128
#define WW 128
#define NPIX (128*128)
#define NANCH (NPIX*6)
#define KPRE 6000
#define KPOST 300
#define SORT_CAP 16384
#define RW 96            /* u64 words per bitmap row */
#define NMS_T 0.7f

#define OUT_PROB 1500
#define OUT_BBOX (1500 + 98304)

/* ---------------- ws layout (bytes) ----------------
   conv1: 0 .. 33.5MB (live during conv3+conv1)
   wt   : 33.5MB .. 52.4MB (live only during conv3)
   post-conv3 buffers alias the wt region (k_init runs AFTER conv3). */
#define WS_CONV1 ((size_t)0)                     /* 512*16384*4 = 33554432 */
#define WS_WT    ((size_t)33554432)              /* 9216*512*4  = 18874368 */
#define WS_BOXES ((size_t)33554432)              /* 98304*16    = 1572864  */
#define WS_SCORE (WS_BOXES + 1572864)            /* 98304*4     = 393216   */
#define WS_KEYS  (WS_SCORE + 393216)             /* 16384*8     = 131072   */
#define WS_TB    (WS_KEYS + 131072)              /* 6144*16     = 98304    */
#define WS_AREA  (WS_TB + 98304)                 /* 6144*4      = 24576    */
#define WS_SUP   (WS_AREA + 24576)               /* 6144*96*8   = 4718592  */
#define WS_HIST  (WS_SUP + 4718592)              /* 65536*4     = 262144   */
#define WS_CTRL  (WS_HIST + 262144)              /* pad 256                */
#define WS_KEEP  (WS_CTRL + 256)                 /* pad 1280               */
#define WS_SKEYS (WS_KEEP + 1280)                /* 6144*8      = 49152    */
/* total needed = 52428800 bytes */

/* bank swizzle: block b -> b ^ ((b>>4)&1); keeps 4-word blocks intact */
__device__ __forceinline__ int swb(int b) { return b ^ ((b >> 4) & 1); }

/* ---------------- init (runs AFTER conv3; aliases wt region) ---------------- */
__global__ void k_init(u32* __restrict__ hist, u32* __restrict__ ctrl,
                       int* __restrict__ keep, u64* __restrict__ keys) {
    int t = blockIdx.x * blockDim.x + threadIdx.x;
    if (t < 65536) hist[t] = 0u;
    if (t < 64)    ctrl[t] = 0u;
    if (t < 304)   keep[t] = -1;
    if (t < SORT_CAP) keys[t] = ~0ULL;
}

/* ---------------- weight transpose: w[512][9216] -> wt[9216][512] ---------------- */
__global__ __launch_bounds__(256) void k_wt(const float* __restrict__ w,
                                            float* __restrict__ wt) {
    __shared__ float T[64][65];
    const int k0  = blockIdx.x * 64;   /* 144 blocks */
    const int oc0 = blockIdx.y * 64;   /* 8 blocks   */
    const int c = threadIdx.x & 63;
    const int r = threadIdx.x >> 6;
#pragma unroll
    for (int i = 0; i < 16; ++i) {
        int rr = r + i * 4;
        T[rr][c] = w[(size_t)(oc0 + rr) * 9216 + k0 + c];
    }
    __syncthreads();
#pragma unroll
    for (int i = 0; i < 16; ++i) {
        int rr = r + i * 4;
        wt[(size_t)(k0 + rr) * 512 + oc0 + c] = T[c][rr];
    }
}

/* ---------------- conv 3x3, 1024->512, pad 1, relu ----------------
   grid (128 rows, 4 oc-tiles), 256 thr. Block: 128 oc x 128 px row.
   Thread: 8 oc x 8 px. Software-pipelined: global loads for cc+1 are in
   flight across cc's compute phase; fully-unrolled cp loop gives all
   ds_reads immediate offsets. */
__global__ __launch_bounds__(256, 2) void k_conv3(const float* __restrict__ in,
                                                  const float* __restrict__ wt,
                                                  const float* __restrict__ bias,
                                                  float* __restrict__ out) {
    const int y   = blockIdx.x;
    const int oc0 = blockIdx.y * 128;
    const int tid = threadIdx.x;
    const int og  = tid >> 4;   /* 0..15 -> oc = og*8 */
    const int pg  = tid & 15;   /* px = pg*8 */

    __shared__ __align__(16) float Xl[24 * 132];   /* [cp*3+dy][132 swizzled] 12.7KB */
    __shared__ __align__(16) float Wl[72 * 132];   /* [cp*9+r][oc 0..127]     38.0KB */

    /* one-time zero (halo cols + OOB rows stay zero forever) */
    for (int u = tid; u < 24 * 132; u += 256) Xl[u] = 0.f;

    const int q  = tid >> 5;   /* 0..7 */
    const int c4 = tid & 31;   /* float4 col-block */

    /* X staging precompute: slot i handles row q+8i, cols 4*c4+1..4*c4+4 */
    int xg[3], xa[3], xb[3];
    bool xok[3];
#pragma unroll
    for (int i = 0; i < 3; ++i) {
        int row = q + 8 * i;              /* cp*3+dy */
        int cp = row / 3, dy = row - cp * 3;
        int yy = y + dy - 1;
        xok[i] = (yy >= 0 && yy < HH);
        xg[i] = cp * NPIX + (xok[i] ? yy : 0) * WW + c4 * 4;
        xa[i] = row * 132 + swb(c4) * 4;       /* words +1..+3 */
        xb[i] = row * 132 + swb(c4 + 1) * 4;   /* word  +0     */
    }
    /* W staging: slot i -> row q+8i, oc-block c4 */
    const int wg0 = q * 512 + oc0 + c4 * 4;
    const int wl0 = q * 132 + c4 * 4;

    /* swizzled read offsets (thread-invariant) */
    const int xo0 = swb(2 * pg) * 4;
    const int xo1 = swb(2 * pg + 1) * 4;
    const int xo2 = swb(2 * pg + 2) * 4;
    const int wbase = og * 8;

    float acc[8][8];
#pragma unroll
    for (int o = 0; o < 8; ++o)
#pragma unroll
        for (int j = 0; j < 8; ++j) acc[o][j] = 0.f;

    const float* inp = in;
    const float* wtp = wt;

    /* preload cc=0 into registers */
    float4 xf[3], wf[9];
#pragma unroll
    for (int i = 0; i < 3; ++i)
        if (xok[i]) xf[i] = *(const float4*)(inp + xg[i]);
#pragma unroll
    for (int i = 0; i < 9; ++i)
        wf[i] = *(const float4*)(wtp + wg0 + i * 4096);

    __syncthreads();   /* zero-init visible */

    for (int cc = 0; cc < 128; ++cc) {
        /* write staged regs to LDS */
#pragma unroll
        for (int i = 0; i < 3; ++i)
            if (xok[i]) {
                Xl[xa[i] + 1] = xf[i].x;
                Xl[xa[i] + 2] = xf[i].y;
                Xl[xa[i] + 3] = xf[i].z;
                Xl[xb[i]]     = xf[i].w;
            }
#pragma unroll
        for (int i = 0; i < 9; ++i)
            *(float4*)&Wl[wl0 + i * 1056] = wf[i];
        __syncthreads();

        /* prefetch cc+1 (in flight across the whole compute phase) */
        if (cc + 1 < 128) {
            inp += 8 * NPIX;
            wtp += 72 * 512;
#pragma unroll
            for (int i = 0; i < 3; ++i)
                if (xok[i]) xf[i] = *(const float4*)(inp + xg[i]);
#pragma unroll
            for (int i = 0; i < 9; ++i)
                wf[i] = *(const float4*)(wtp + wg0 + i * 4096);
        }

        /* compute: fully unrolled, all LDS reads at immediate offsets */
#pragma unroll
        for (int cp = 0; cp < 8; ++cp) {
            float v[3][10];
#pragma unroll
            for (int dy = 0; dy < 3; ++dy) {
                const float* xp = &Xl[(cp * 3 + dy) * 132];
                float4 pa = *(const float4*)(xp + xo0);
                float4 pb = *(const float4*)(xp + xo1);
                float2 pc = *(const float2*)(xp + xo2);
                v[dy][0] = pa.x; v[dy][1] = pa.y; v[dy][2] = pa.z; v[dy][3] = pa.w;
                v[dy][4] = pb.x; v[dy][5] = pb.y; v[dy][6] = pb.z; v[dy][7] = pb.w;
                v[dy][8] = pc.x; v[dy][9] = pc.y;
            }
#pragma unroll
            for (int r = 0; r < 9; ++r) {
                const int dy = r / 3, dx = r % 3;
                const float* wp = &Wl[(cp * 9 + r) * 132 + wbase];
                const float4 w0 = *(const float4*)wp;
                const float4 w1 = *(const float4*)(wp + 4);
#pragma unroll
                for (int j = 0; j < 8; ++j) {
                    const float xv = v[dy][j + dx];
                    acc[0][j] = fmaf(w0.x, xv, acc[0][j]);
                    acc[1][j] = fmaf(w0.y, xv, acc[1][j]);
                    acc[2][j] = fmaf(w0.z, xv, acc[2][j]);
                    acc[3][j] = fmaf(w0.w, xv, acc[3][j]);
                    acc[4][j] = fmaf(w1.x, xv, acc[4][j]);
                    acc[5][j] = fmaf(w1.y, xv, acc[5][j]);
                    acc[6][j] = fmaf(w1.z, xv, acc[6][j]);
                    acc[7][j] = fmaf(w1.w, xv, acc[7][j]);
                }
            }
        }
        __syncthreads();
    }
#pragma unroll
    for (int o = 0; o < 8; ++o) {
        const int oc = oc0 + og * 8 + o;
        const float b = bias[oc];
        float4 r0, r1;
        r0.x = fmaxf(acc[o][0] + b, 0.f);
        r0.y = fmaxf(acc[o][1] + b, 0.f);
        r0.z = fmaxf(acc[o][2] + b, 0.f);
        r0.w = fmaxf(acc[o][3] + b, 0.f);
        r1.x = fmaxf(acc[o][4] + b, 0.f);
        r1.y = fmaxf(acc[o][5] + b, 0.f);
        r1.z = fmaxf(acc[o][6] + b, 0.f);
        r1.w = fmaxf(acc[o][7] + b, 0.f);
        float* op = &out[(size_t)oc * NPIX + y * WW + pg * 8];
        *(float4*)op = r0;
        *(float4*)(op + 4) = r1;
    }
}

/* ---------------- fused 1x1 convs (cls 6 + bbox 24) + pair softmax ---------------- */
__global__ __launch_bounds__(256) void k_conv1(const float* __restrict__ conv1,
                                               const float* __restrict__ wcls,
                                               const float* __restrict__ bcls,
                                               const float* __restrict__ wbox,
                                               const float* __restrict__ bboxb,
                                               float* __restrict__ out) {
    const int tid = threadIdx.x;
    const int og = tid >> 4, pg = tid & 15;
    const int px0 = blockIdx.x * 64;
    __shared__ __align__(16) float Wl[32][32];
    __shared__ __align__(16) float Xl[32][64];
    __shared__ float Sc[6][64];

    float a0[4] = {0, 0, 0, 0}, a1[4] = {0, 0, 0, 0};

    for (int cc = 0; cc < 16; ++cc) {
        {
            int u = tid;
            int row = (u * 4) >> 5;
            int col = (u * 4) & 31;
            float4 v;
            if (row < 6)       v = *(const float4*)(wcls + row * 512 + cc * 32 + col);
            else if (row < 30) v = *(const float4*)(wbox + (row - 6) * 512 + cc * 32 + col);
            else               v = make_float4(0.f, 0.f, 0.f, 0.f);
            *(float4*)&Wl[row][col] = v;
        }
        for (int u = tid; u < 512; u += 256) {
            int row = (u * 4) >> 6, col = (u * 4) & 63;
            *(float4*)&Xl[row][col] =
                *(const float4*)(conv1 + (size_t)(cc * 32 + row) * NPIX + px0 + col);
        }
        __syncthreads();
#pragma unroll
        for (int cp = 0; cp < 32; ++cp) {
            const float4 x = *(const float4*)&Xl[cp][pg * 4];
            const float w0 = Wl[og][cp];
            const float w1 = Wl[og + 16][cp];
            a0[0] = fmaf(w0, x.x, a0[0]); a0[1] = fmaf(w0, x.y, a0[1]);
            a0[2] = fmaf(w0, x.z, a0[2]); a0[3] = fmaf(w0, x.w, a0[3]);
            a1[0] = fmaf(w1, x.x, a1[0]); a1[1] = fmaf(w1, x.y, a1[1]);
            a1[2] = fmaf(w1, x.z, a1[2]); a1[3] = fmaf(w1, x.w, a1[3]);
        }
        __syncthreads();
    }
    const int pxb = px0 + pg * 4;
    if (og < 6) {
        const float bc = bcls[og];
#pragma unroll
        for (int kk = 0; kk < 4; ++kk) Sc[og][pg * 4 + kk] = a0[kk] + bc;
    } else {
        const float bb = bboxb[og - 6];
#pragma unroll
        for (int kk = 0; kk < 4; ++kk)
            out[OUT_BBOX + (size_t)(og - 6) * NPIX + pxb + kk] = a0[kk] + bb;
    }
    if (og + 16 < 30) {
        const float bb = bboxb[og + 10];
#pragma unroll
        for (int kk = 0; kk < 4; ++kk)
            out[OUT_BBOX + (size_t)(og + 10) * NPIX + pxb + kk] = a1[kk] + bb;
    }
    __syncthreads();
    if (og < 6) {
        const int pa = og < 3 ? og + 3 : og - 3;
#pragma unroll
        for (int kk = 0; kk < 4; ++kk) {
            const float s = Sc[og][pg * 4 + kk], sp = Sc[pa][pg * 4 + kk];
            out[OUT_PROB + (size_t)og * NPIX + pxb + kk] = 1.0f / (1.0f + expf(sp - s));
        }
    }
}

/* ---------------- anchor decode + clip ---------------- */
__global__ void k_decode(const float* __restrict__ out, const float* __restrict__ meta,
                         float4* __restrict__ boxes, float* __restrict__ scores) {
#pragma clang fp contract(off)
    int t = blockIdx.x * blockDim.x + threadIdx.x;
    if (t >= NANCH) return;
    int a = t >> 14;
    int pix = t & 16383;
    int yc = pix >> 7, xc = pix & 127;
    int n = pix * 6 + a;
    float sc = out[OUT_PROB + (size_t)a * NPIX + pix];
    float d0 = out[OUT_BBOX + (size_t)(a * 4 + 0) * NPIX + pix];
    float d1 = out[OUT_BBOX + (size_t)(a * 4 + 1) * NPIX + pix];
    float d2 = out[OUT_BBOX + (size_t)(a * 4 + 2) * NPIX + pix];
    float d3 = out[OUT_BBOX + (size_t)(a * 4 + 3) * NPIX + pix];
    const float dims = (float)(16 << a);
    const float cxa = (xc + 0.5f) * 16.f;
    const float cya = (yc + 0.5f) * 16.f;
    float pcx = d0 * dims + cxa;
    float pcy = d1 * dims + cya;
    float pw  = expf(d2) * dims;
    float ph  = expf(d3) * dims;
    float imh = meta[0], imw = meta[1];
    float x1 = fminf(fmaxf(pcx - 0.5f * pw, 0.f), imw);
    float y1 = fminf(fmaxf(pcy - 0.5f * ph, 0.f), imh);
    float x2 = fminf(fmaxf(pcx + 0.5f * pw, 0.f), imw);
    float y2 = fminf(fmaxf(pcy + 0.5f * ph, 0.f), imh);
    boxes[n] = make_float4(x1, y1, x2, y2);
    scores[n] = sc;
}

/* ---------------- histogram on top-16 bits of score ---------------- */
__global__ void k_hist(const float* __restrict__ scores, u32* __restrict__ hist) {
    int t = blockIdx.x * blockDim.x + threadIdx.x;
    if (t >= NANCH) return;
    u32 b = __float_as_uint(scores[t]) >> 16;
    atomicAdd(&hist[b], 1u);
}

/* ---------------- find threshold bin (6000th largest) ---------------- */
__global__ void k_select(const u32* __restrict__ hist, u32* __restrict__ ctrl) {
    __shared__ u32 S[256];
    __shared__ u32 U[256];
    const int tid = threadIdx.x;
    u32 s = 0;
    for (int i = 0; i < 256; ++i) s += hist[tid * 256 + i];
    S[tid] = s;
    __syncthreads();
    if (tid == 0) {
        u32 acc = 0;
        for (int t = 255; t >= 0; --t) { U[t] = acc; acc += S[t]; }
    }
    __syncthreads();
    if (U[tid] < KPRE && U[tid] + S[tid] >= KPRE) {
        u32 acc = U[tid];
        for (int b = tid * 256 + 255; b >= tid * 256; --b) {
            u32 h = hist[b];
            if (acc + h >= KPRE) { ctrl[1] = (u32)b; ctrl[2] = acc; break; }
            acc += h;
        }
    }
}

/* ---------------- compact candidates ---------------- */
__global__ void k_compact(const float* __restrict__ scores, u32* __restrict__ ctrl,
                          u64* __restrict__ keys) {
    int t = blockIdx.x * blockDim.x + threadIdx.x;
    if (t >= NANCH) return;
    u32 bits = __float_as_uint(scores[t]);
    if ((bits >> 16) >= ctrl[1]) {
        u32 pos = atomicAdd(&ctrl[0], 1u);
        if (pos < SORT_CAP) keys[pos] = ((u64)(~bits) << 32) | (u32)t;
    }
}

/* ---------------- bitonic sort of 8192-key chunk in LDS ---------------- */
__global__ __launch_bounds__(1024) void k_sort_local(u64* __restrict__ keys) {
    __shared__ u64 lds[8192];
    const int tid = threadIdx.x;
    u64* g = keys + blockIdx.x * 8192;
    for (int u = tid; u < 8192; u += 1024) lds[u] = g[u];
    __syncthreads();
    for (int k = 2; k <= 8192; k <<= 1) {
        for (int j = k >> 1; j > 0; j >>= 1) {
            for (int u = tid; u < 4096; u += 1024) {
                int i = ((u & ~(j - 1)) << 1) | (u & (j - 1));
                int l = i | j;
                bool up = (i & k) == 0;
                u64 x = lds[i], y2 = lds[l];
                if ((x > y2) == up) { lds[i] = y2; lds[l] = x; }
            }
            __syncthreads();
        }
    }
    for (int u = tid; u < 8192; u += 1024) g[u] = lds[u];
}

/* ---------------- merge-path: first 6000 of two sorted 8192 runs ---------------- */
__global__ void k_merge(const u64* __restrict__ keys, u64* __restrict__ skeys) {
    int i = blockIdx.x * blockDim.x + threadIdx.x;
    if (i >= KPRE) return;
    const u64* A = keys;
    const u64* B = keys + 8192;
    int lo = i > 8192 ? i - 8192 : 0;
    int hi = i < 8192 ? i : 8192;
    while (lo < hi) {
        int a = (lo + hi) >> 1;
        if (A[a] < B[i - a - 1]) lo = a + 1; else hi = a;
    }
    int a = lo, b = i - lo;
    u64 va = (a < 8192) ? A[a] : ~0ULL;
    u64 vb = (b < 8192) ? B[b] : ~0ULL;
    skeys[i] = va < vb ? va : vb;
}

/* ---------------- gather top boxes + areas ---------------- */
__global__ void k_gather(const u64* __restrict__ skeys, const float4* __restrict__ boxes,
                         float4* __restrict__ tb, float* __restrict__ areas) {
#pragma clang fp contract(off)
    int i = blockIdx.x * blockDim.x + threadIdx.x;
    if (i >= KPRE) return;
    u32 n = (u32)(skeys[i] & 0xFFFFFFFFULL);
    float4 b = boxes[n];
    tb[i] = b;
    areas[i] = fmaxf(b.z - b.x, 0.f) * fmaxf(b.w - b.y, 0.f);
}

/* ---------------- suppression bitmap ---------------- */
__global__ __launch_bounds__(256) void k_bitmap(const float4* __restrict__ tb,
                                                const float* __restrict__ areas,
                                                u64* __restrict__ suppr) {
#pragma clang fp contract(off)
    const int i = blockIdx.x;
    const int lane = threadIdx.x & 63;
    const int wv = threadIdx.x >> 6;
    const float4 bi = tb[i];
    const float ai = areas[i];
    for (int Wd = wv; Wd < RW; Wd += 4) {
        int j = Wd * 64 + lane;
        bool sup = false;
        if (j < KPRE) {
            float4 bj = tb[j];
            float iw = fmaxf(fminf(bi.z, bj.z) - fmaxf(bi.x, bj.x), 0.f);
            float ih = fmaxf(fminf(bi.w, bj.w) - fmaxf(bi.y, bj.y), 0.f);
            float inter = iw * ih;
            float denom = ((areas[j] + ai) - inter) + 1e-9f;
            sup = (inter / denom) > NMS_T;
        }
        u64 m = __ballot(sup);
        if (lane == 0) suppr[(size_t)i * RW + Wd] = m;
    }
}

/* ---------------- greedy scan over bitmap ---------------- */
__global__ void k_scan(const u64* __restrict__ suppr, int* __restrict__ keep) {
    const int lane = threadIdx.x; /* 64 threads */
    u64 a0 = (lane < 93) ? ~0ULL : (lane == 93 ? ((1ULL << 48) - 1) : 0ULL);
    const int w1 = lane + 64;
    u64 a1 = (w1 < 93) ? ~0ULL : (w1 == 93 ? ((1ULL << 48) - 1) : 0ULL);
    int kept = 0;
    int i = 0;
    while (kept < KPOST) {
        int wi = i >> 6;
        if (wi >= 94) break;
        u64 wvv = (wi < 64) ? __shfl(a0, wi) : __shfl(a1, wi - 64);
        wvv &= (~0ULL) << (i & 63);
        if (wvv == 0ULL) { i = (wi + 1) << 6; continue; }
        int b = __ffsll((long long)wvv) - 1;
        i = (wi << 6) + b;
        if (lane == 0) keep[kept] = i;
        kept++;
        const u64* row = suppr + (size_t)i * RW;
        u64 s0 = row[lane];
        u64 s1 = (lane + 64 < RW) ? row[lane + 64] : 0ULL;
        a0 &= ~s0;
        a1 &= ~s1;
        i++;
    }
}

/* ---------------- write rois ---------------- */
__global__ void k_rois(const int* __restrict__ keep, const float4* __restrict__ tb,
                       float* __restrict__ out) {
    int r = blockIdx.x * blockDim.x + threadIdx.x;
    if (r >= KPOST) return;
    int k = keep[r];
    float4 b = make_float4(0.f, 0.f, 0.f, 0.f);
    if (k >= 0) b = tb[k];
    out[r * 5 + 0] = 0.f;
    out[r * 5 + 1] = b.x;
    out[r * 5 + 2] = b.y;
    out[r * 5 + 3] = b.z;
    out[r * 5 + 4] = b.w;
}

extern "C" void kernel_launch(void* const* d_in, const int* in_sizes, int n_in,
                              void* d_out, int out_size, void* d_ws, size_t ws_size,
                              hipStream_t stream) {
    (void)in_sizes; (void)n_in; (void)out_size; (void)ws_size;
    const float* x     = (const float*)d_in[0];
    const float* meta  = (const float*)d_in[1];
    const float* wc3   = (const float*)d_in[3];
    const float* bc3   = (const float*)d_in[4];
    const float* wcls  = (const float*)d_in[5];
    const float* bcls  = (const float*)d_in[6];
    const float* wbox  = (const float*)d_in[7];
    const float* bboxb = (const float*)d_in[8];
    float* out = (float*)d_out;
    char* ws = (char*)d_ws;

    float*  conv1  = (float*)(ws + WS_CONV1);
    float*  wt     = (float*)(ws + WS_WT);
    float4* boxes  = (float4*)(ws + WS_BOXES);
    float*  scores = (float*)(ws + WS_SCORE);
    u64*    keys   = (u64*)(ws + WS_KEYS);
    float4* tb     = (float4*)(ws + WS_TB);
    float*  areas  = (float*)(ws + WS_AREA);
    u64*    suppr  = (u64*)(ws + WS_SUP);
    u32*    hist   = (u32*)(ws + WS_HIST);
    u32*    ctrl   = (u32*)(ws + WS_CTRL);
    int*    keep   = (int*)(ws + WS_KEEP);
    u64*    skeys  = (u64*)(ws + WS_SKEYS);

    k_wt<<<dim3(144, 8), 256, 0, stream>>>(wc3, wt);
    k_conv3<<<dim3(128, 4), 256, 0, stream>>>(x, wt, bc3, conv1);
    k_init<<<256, 256, 0, stream>>>(hist, ctrl, keep, keys);   /* after conv3: aliases wt */
    k_conv1<<<256, 256, 0, stream>>>(conv1, wcls, bcls, wbox, bboxb, out);
    k_decode<<<384, 256, 0, stream>>>(out, meta, boxes, scores);
    k_hist<<<384, 256, 0, stream>>>(scores, hist);
    k_select<<<1, 256, 0, stream>>>(hist, ctrl);
    k_compact<<<384, 256, 0, stream>>>(scores, ctrl, keys);
    k_sort_local<<<2, 1024, 0, stream>>>(keys);
    k_merge<<<24, 256, 0, stream>>>(keys, skeys);
    k_gather<<<24, 256, 0, stream>>>(skeys, boxes, tb, areas);
    k_bitmap<<<6000, 256, 0, stream>>>(tb, areas, suppr);
    k_scan<<<1, 64, 0, stream>>>(suppr, keep);
    k_rois<<<2, 256, 0, stream>>>(keep, tb, out);
}

// Round 4
// 2573.791 us; speedup vs baseline: 1.0339x; 1.0339x over previous
//
#include <hip/hip_runtime.h>
#include <math.h>

typedef unsigned int u32;
typedef unsigned long long u64;

#define HH 128
#define WW 128
#define NPIX (128*128)
#define NANCH (NPIX*6)
#define KPRE 6000
#define KPOST 300
#define SORT_CAP 16384
#define RW 96            /* u64 words per bitmap row */
#define NMS_T 0.7f

#define OUT_PROB 1500
#define OUT_BBOX (1500 + 98304)

/* ---------------- ws layout (bytes) ----------------
   conv1: 0 .. 33.5MB (live during conv3+conv1)
   wt   : 33.5MB .. 52.4MB (live only during conv3)
   post-conv3 buffers alias the wt region (k_init runs AFTER conv3). */
#define WS_CONV1 ((size_t)0)                     /* 512*16384*4 = 33554432 */
#define WS_WT    ((size_t)33554432)              /* 9216*512*4  = 18874368 */
#define WS_BOXES ((size_t)33554432)              /* 98304*16    = 1572864  */
#define WS_SCORE (WS_BOXES + 1572864)            /* 98304*4     = 393216   */
#define WS_KEYS  (WS_SCORE + 393216)             /* 16384*8     = 131072   */
#define WS_TB    (WS_KEYS + 131072)              /* 6144*16     = 98304    */
#define WS_AREA  (WS_TB + 98304)                 /* 6144*4      = 24576    */
#define WS_SUP   (WS_AREA + 24576)               /* 6144*96*8   = 4718592  */
#define WS_HIST  (WS_SUP + 4718592)              /* 65536*4     = 262144   */
#define WS_CTRL  (WS_HIST + 262144)              /* pad 256                */
#define WS_KEEP  (WS_CTRL + 256)                 /* pad 1280               */
#define WS_SKEYS (WS_KEEP + 1280)                /* 6144*8      = 49152    */
/* total needed = 52428800 bytes */

/* bank swizzle: block b -> b ^ ((b>>4)&1); keeps 4-word blocks intact */
__device__ __forceinline__ int swb(int b) { return b ^ ((b >> 4) & 1); }

/* ---------------- init (runs AFTER conv3; aliases wt region) ---------------- */
__global__ void k_init(u32* __restrict__ hist, u32* __restrict__ ctrl,
                       int* __restrict__ keep, u64* __restrict__ keys) {
    int t = blockIdx.x * blockDim.x + threadIdx.x;
    if (t < 65536) hist[t] = 0u;
    if (t < 64)    ctrl[t] = 0u;
    if (t < 304)   keep[t] = -1;
    if (t < SORT_CAP) keys[t] = ~0ULL;
}

/* ---------------- weight transpose: w[512][9216] -> wt[9216][512] ---------------- */
__global__ __launch_bounds__(256) void k_wt(const float* __restrict__ w,
                                            float* __restrict__ wt) {
    __shared__ float T[64][65];
    const int k0  = blockIdx.x * 64;   /* 144 blocks */
    const int oc0 = blockIdx.y * 64;   /* 8 blocks   */
    const int c = threadIdx.x & 63;
    const int r = threadIdx.x >> 6;
#pragma unroll
    for (int i = 0; i < 16; ++i) {
        int rr = r + i * 4;
        T[rr][c] = w[(size_t)(oc0 + rr) * 9216 + k0 + c];
    }
    __syncthreads();
#pragma unroll
    for (int i = 0; i < 16; ++i) {
        int rr = r + i * 4;
        wt[(size_t)(k0 + rr) * 512 + oc0 + c] = T[c][rr];
    }
}

/* ---------------- conv 3x3, 1024->512, pad 1, relu ----------------
   grid (128 rows, 4 oc-tiles), 256 thr. Block: 128 oc x 128 px row.
   Thread: 8 oc x 8 px. Software-pipelined (register prefetch of cc+1),
   cp loop kept at unroll 1 to bound register pressure (full unroll
   spilled accs -> 1.7 GB scratch traffic in R3). */
__global__ __launch_bounds__(256, 2) void k_conv3(const float* __restrict__ in,
                                                  const float* __restrict__ wt,
                                                  const float* __restrict__ bias,
                                                  float* __restrict__ out) {
    const int y   = blockIdx.x;
    const int oc0 = blockIdx.y * 128;
    const int tid = threadIdx.x;
    const int og  = tid >> 4;   /* 0..15 -> oc = og*8 */
    const int pg  = tid & 15;   /* px = pg*8 */

    __shared__ __align__(16) float Xl[24 * 132];   /* [cp*3+dy][132 swizzled] 12.7KB */
    __shared__ __align__(16) float Wl[72 * 132];   /* [cp*9+r][oc 0..127]     38.0KB */

    /* one-time zero (halo cols + OOB rows stay zero forever) */
    for (int u = tid; u < 24 * 132; u += 256) Xl[u] = 0.f;

    const int q  = tid >> 5;   /* 0..7 */
    const int c4 = tid & 31;   /* float4 col-block */

    /* X staging precompute: slot i handles row q+8i, cols 4*c4+1..4*c4+4 */
    int xg[3], xa[3], xb[3];
    bool xok[3];
#pragma unroll
    for (int i = 0; i < 3; ++i) {
        int row = q + 8 * i;              /* cp*3+dy */
        int cp = row / 3, dy = row - cp * 3;
        int yy = y + dy - 1;
        xok[i] = (yy >= 0 && yy < HH);
        xg[i] = cp * NPIX + (xok[i] ? yy : 0) * WW + c4 * 4;
        xa[i] = row * 132 + swb(c4) * 4;       /* words +1..+3 */
        xb[i] = row * 132 + swb(c4 + 1) * 4;   /* word  +0     */
    }
    /* W staging: slot i -> row q+8i, oc-block c4 */
    const int wg0 = q * 512 + oc0 + c4 * 4;
    const int wl0 = q * 132 + c4 * 4;

    /* swizzled read offsets (thread-invariant) */
    const int xo0 = swb(2 * pg) * 4;
    const int xo1 = swb(2 * pg + 1) * 4;
    const int xo2 = swb(2 * pg + 2) * 4;
    const int wbase = og * 8;

    float acc[8][8];
#pragma unroll
    for (int o = 0; o < 8; ++o)
#pragma unroll
        for (int j = 0; j < 8; ++j) acc[o][j] = 0.f;

    const float* inp = in;
    const float* wtp = wt;

    /* preload cc=0 into registers */
    float4 xf[3], wf[9];
#pragma unroll
    for (int i = 0; i < 3; ++i)
        if (xok[i]) xf[i] = *(const float4*)(inp + xg[i]);
#pragma unroll
    for (int i = 0; i < 9; ++i)
        wf[i] = *(const float4*)(wtp + wg0 + i * 4096);

    __syncthreads();   /* zero-init visible */

    for (int cc = 0; cc < 128; ++cc) {
        /* write staged regs to LDS */
#pragma unroll
        for (int i = 0; i < 3; ++i)
            if (xok[i]) {
                Xl[xa[i] + 1] = xf[i].x;
                Xl[xa[i] + 2] = xf[i].y;
                Xl[xa[i] + 3] = xf[i].z;
                Xl[xb[i]]     = xf[i].w;
            }
#pragma unroll
        for (int i = 0; i < 9; ++i)
            *(float4*)&Wl[wl0 + i * 1056] = wf[i];
        __syncthreads();

        /* prefetch cc+1 (in flight across the whole compute phase) */
        if (cc + 1 < 128) {
            inp += 8 * NPIX;
            wtp += 72 * 512;
#pragma unroll
            for (int i = 0; i < 3; ++i)
                if (xok[i]) xf[i] = *(const float4*)(inp + xg[i]);
#pragma unroll
            for (int i = 0; i < 9; ++i)
                wf[i] = *(const float4*)(wtp + wg0 + i * 4096);
        }

        /* compute: unroll 1 keeps live-range bounded (no spill) */
#pragma unroll 1
        for (int cp = 0; cp < 8; ++cp) {
            float v[3][10];
#pragma unroll
            for (int dy = 0; dy < 3; ++dy) {
                const float* xp = &Xl[(cp * 3 + dy) * 132];
                float4 pa = *(const float4*)(xp + xo0);
                float4 pb = *(const float4*)(xp + xo1);
                float2 pc = *(const float2*)(xp + xo2);
                v[dy][0] = pa.x; v[dy][1] = pa.y; v[dy][2] = pa.z; v[dy][3] = pa.w;
                v[dy][4] = pb.x; v[dy][5] = pb.y; v[dy][6] = pb.z; v[dy][7] = pb.w;
                v[dy][8] = pc.x; v[dy][9] = pc.y;
            }
#pragma unroll
            for (int r = 0; r < 9; ++r) {
                const int dy = r / 3, dx = r % 3;
                const float* wp = &Wl[(cp * 9 + r) * 132 + wbase];
                const float4 w0 = *(const float4*)wp;
                const float4 w1 = *(const float4*)(wp + 4);
#pragma unroll
                for (int j = 0; j < 8; ++j) {
                    const float xv = v[dy][j + dx];
                    acc[0][j] = fmaf(w0.x, xv, acc[0][j]);
                    acc[1][j] = fmaf(w0.y, xv, acc[1][j]);
                    acc[2][j] = fmaf(w0.z, xv, acc[2][j]);
                    acc[3][j] = fmaf(w0.w, xv, acc[3][j]);
                    acc[4][j] = fmaf(w1.x, xv, acc[4][j]);
                    acc[5][j] = fmaf(w1.y, xv, acc[5][j]);
                    acc[6][j] = fmaf(w1.z, xv, acc[6][j]);
                    acc[7][j] = fmaf(w1.w, xv, acc[7][j]);
                }
            }
        }
        __syncthreads();
    }
#pragma unroll
    for (int o = 0; o < 8; ++o) {
        const int oc = oc0 + og * 8 + o;
        const float b = bias[oc];
        float4 r0, r1;
        r0.x = fmaxf(acc[o][0] + b, 0.f);
        r0.y = fmaxf(acc[o][1] + b, 0.f);
        r0.z = fmaxf(acc[o][2] + b, 0.f);
        r0.w = fmaxf(acc[o][3] + b, 0.f);
        r1.x = fmaxf(acc[o][4] + b, 0.f);
        r1.y = fmaxf(acc[o][5] + b, 0.f);
        r1.z = fmaxf(acc[o][6] + b, 0.f);
        r1.w = fmaxf(acc[o][7] + b, 0.f);
        float* op = &out[(size_t)oc * NPIX + y * WW + pg * 8];
        *(float4*)op = r0;
        *(float4*)(op + 4) = r1;
    }
}

/* ---------------- fused 1x1 convs (cls 6 + bbox 24) + pair softmax ---------------- */
__global__ __launch_bounds__(256) void k_conv1(const float* __restrict__ conv1,
                                               const float* __restrict__ wcls,
                                               const float* __restrict__ bcls,
                                               const float* __restrict__ wbox,
                                               const float* __restrict__ bboxb,
                                               float* __restrict__ out) {
    const int tid = threadIdx.x;
    const int og = tid >> 4, pg = tid & 15;
    const int px0 = blockIdx.x * 64;
    __shared__ __align__(16) float Wl[32][32];
    __shared__ __align__(16) float Xl[32][64];
    __shared__ float Sc[6][64];

    float a0[4] = {0, 0, 0, 0}, a1[4] = {0, 0, 0, 0};

    for (int cc = 0; cc < 16; ++cc) {
        {
            int u = tid;
            int row = (u * 4) >> 5;
            int col = (u * 4) & 31;
            float4 v;
            if (row < 6)       v = *(const float4*)(wcls + row * 512 + cc * 32 + col);
            else if (row < 30) v = *(const float4*)(wbox + (row - 6) * 512 + cc * 32 + col);
            else               v = make_float4(0.f, 0.f, 0.f, 0.f);
            *(float4*)&Wl[row][col] = v;
        }
        for (int u = tid; u < 512; u += 256) {
            int row = (u * 4) >> 6, col = (u * 4) & 63;
            *(float4*)&Xl[row][col] =
                *(const float4*)(conv1 + (size_t)(cc * 32 + row) * NPIX + px0 + col);
        }
        __syncthreads();
#pragma unroll
        for (int cp = 0; cp < 32; ++cp) {
            const float4 x = *(const float4*)&Xl[cp][pg * 4];
            const float w0 = Wl[og][cp];
            const float w1 = Wl[og + 16][cp];
            a0[0] = fmaf(w0, x.x, a0[0]); a0[1] = fmaf(w0, x.y, a0[1]);
            a0[2] = fmaf(w0, x.z, a0[2]); a0[3] = fmaf(w0, x.w, a0[3]);
            a1[0] = fmaf(w1, x.x, a1[0]); a1[1] = fmaf(w1, x.y, a1[1]);
            a1[2] = fmaf(w1, x.z, a1[2]); a1[3] = fmaf(w1, x.w, a1[3]);
        }
        __syncthreads();
    }
    const int pxb = px0 + pg * 4;
    if (og < 6) {
        const float bc = bcls[og];
#pragma unroll
        for (int kk = 0; kk < 4; ++kk) Sc[og][pg * 4 + kk] = a0[kk] + bc;
    } else {
        const float bb = bboxb[og - 6];
#pragma unroll
        for (int kk = 0; kk < 4; ++kk)
            out[OUT_BBOX + (size_t)(og - 6) * NPIX + pxb + kk] = a0[kk] + bb;
    }
    if (og + 16 < 30) {
        const float bb = bboxb[og + 10];
#pragma unroll
        for (int kk = 0; kk < 4; ++kk)
            out[OUT_BBOX + (size_t)(og + 10) * NPIX + pxb + kk] = a1[kk] + bb;
    }
    __syncthreads();
    if (og < 6) {
        const int pa = og < 3 ? og + 3 : og - 3;
#pragma unroll
        for (int kk = 0; kk < 4; ++kk) {
            const float s = Sc[og][pg * 4 + kk], sp = Sc[pa][pg * 4 + kk];
            out[OUT_PROB + (size_t)og * NPIX + pxb + kk] = 1.0f / (1.0f + expf(sp - s));
        }
    }
}

/* ---------------- anchor decode + clip ---------------- */
__global__ void k_decode(const float* __restrict__ out, const float* __restrict__ meta,
                         float4* __restrict__ boxes, float* __restrict__ scores) {
#pragma clang fp contract(off)
    int t = blockIdx.x * blockDim.x + threadIdx.x;
    if (t >= NANCH) return;
    int a = t >> 14;
    int pix = t & 16383;
    int yc = pix >> 7, xc = pix & 127;
    int n = pix * 6 + a;
    float sc = out[OUT_PROB + (size_t)a * NPIX + pix];
    float d0 = out[OUT_BBOX + (size_t)(a * 4 + 0) * NPIX + pix];
    float d1 = out[OUT_BBOX + (size_t)(a * 4 + 1) * NPIX + pix];
    float d2 = out[OUT_BBOX + (size_t)(a * 4 + 2) * NPIX + pix];
    float d3 = out[OUT_BBOX + (size_t)(a * 4 + 3) * NPIX + pix];
    const float dims = (float)(16 << a);
    const float cxa = (xc + 0.5f) * 16.f;
    const float cya = (yc + 0.5f) * 16.f;
    float pcx = d0 * dims + cxa;
    float pcy = d1 * dims + cya;
    float pw  = expf(d2) * dims;
    float ph  = expf(d3) * dims;
    float imh = meta[0], imw = meta[1];
    float x1 = fminf(fmaxf(pcx - 0.5f * pw, 0.f), imw);
    float y1 = fminf(fmaxf(pcy - 0.5f * ph, 0.f), imh);
    float x2 = fminf(fmaxf(pcx + 0.5f * pw, 0.f), imw);
    float y2 = fminf(fmaxf(pcy + 0.5f * ph, 0.f), imh);
    boxes[n] = make_float4(x1, y1, x2, y2);
    scores[n] = sc;
}

/* ---------------- histogram on top-16 bits of score ---------------- */
__global__ void k_hist(const float* __restrict__ scores, u32* __restrict__ hist) {
    int t = blockIdx.x * blockDim.x + threadIdx.x;
    if (t >= NANCH) return;
    u32 b = __float_as_uint(scores[t]) >> 16;
    atomicAdd(&hist[b], 1u);
}

/* ---------------- find threshold bin (6000th largest) ---------------- */
__global__ void k_select(const u32* __restrict__ hist, u32* __restrict__ ctrl) {
    __shared__ u32 S[256];
    __shared__ u32 U[256];
    const int tid = threadIdx.x;
    u32 s = 0;
    for (int i = 0; i < 256; ++i) s += hist[tid * 256 + i];
    S[tid] = s;
    __syncthreads();
    if (tid == 0) {
        u32 acc = 0;
        for (int t = 255; t >= 0; --t) { U[t] = acc; acc += S[t]; }
    }
    __syncthreads();
    if (U[tid] < KPRE && U[tid] + S[tid] >= KPRE) {
        u32 acc = U[tid];
        for (int b = tid * 256 + 255; b >= tid * 256; --b) {
            u32 h = hist[b];
            if (acc + h >= KPRE) { ctrl[1] = (u32)b; ctrl[2] = acc; break; }
            acc += h;
        }
    }
}

/* ---------------- compact candidates ---------------- */
__global__ void k_compact(const float* __restrict__ scores, u32* __restrict__ ctrl,
                          u64* __restrict__ keys) {
    int t = blockIdx.x * blockDim.x + threadIdx.x;
    if (t >= NANCH) return;
    u32 bits = __float_as_uint(scores[t]);
    if ((bits >> 16) >= ctrl[1]) {
        u32 pos = atomicAdd(&ctrl[0], 1u);
        if (pos < SORT_CAP) keys[pos] = ((u64)(~bits) << 32) | (u32)t;
    }
}

/* ---------------- bitonic sort of 8192-key chunk in LDS ---------------- */
__global__ __launch_bounds__(1024) void k_sort_local(u64* __restrict__ keys) {
    __shared__ u64 lds[8192];
    const int tid = threadIdx.x;
    u64* g = keys + blockIdx.x * 8192;
    for (int u = tid; u < 8192; u += 1024) lds[u] = g[u];
    __syncthreads();
    for (int k = 2; k <= 8192; k <<= 1) {
        for (int j = k >> 1; j > 0; j >>= 1) {
            for (int u = tid; u < 4096; u += 1024) {
                int i = ((u & ~(j - 1)) << 1) | (u & (j - 1));
                int l = i | j;
                bool up = (i & k) == 0;
                u64 x = lds[i], y2 = lds[l];
                if ((x > y2) == up) { lds[i] = y2; lds[l] = x; }
            }
            __syncthreads();
        }
    }
    for (int u = tid; u < 8192; u += 1024) g[u] = lds[u];
}

/* ---------------- merge-path: first 6000 of two sorted 8192 runs ---------------- */
__global__ void k_merge(const u64* __restrict__ keys, u64* __restrict__ skeys) {
    int i = blockIdx.x * blockDim.x + threadIdx.x;
    if (i >= KPRE) return;
    const u64* A = keys;
    const u64* B = keys + 8192;
    int lo = i > 8192 ? i - 8192 : 0;
    int hi = i < 8192 ? i : 8192;
    while (lo < hi) {
        int a = (lo + hi) >> 1;
        if (A[a] < B[i - a - 1]) lo = a + 1; else hi = a;
    }
    int a = lo, b = i - lo;
    u64 va = (a < 8192) ? A[a] : ~0ULL;
    u64 vb = (b < 8192) ? B[b] : ~0ULL;
    skeys[i] = va < vb ? va : vb;
}

/* ---------------- gather top boxes + areas ---------------- */
__global__ void k_gather(const u64* __restrict__ skeys, const float4* __restrict__ boxes,
                         float4* __restrict__ tb, float* __restrict__ areas) {
#pragma clang fp contract(off)
    int i = blockIdx.x * blockDim.x + threadIdx.x;
    if (i >= KPRE) return;
    u32 n = (u32)(skeys[i] & 0xFFFFFFFFULL);
    float4 b = boxes[n];
    tb[i] = b;
    areas[i] = fmaxf(b.z - b.x, 0.f) * fmaxf(b.w - b.y, 0.f);
}

/* ---------------- suppression bitmap ---------------- */
__global__ __launch_bounds__(256) void k_bitmap(const float4* __restrict__ tb,
                                                const float* __restrict__ areas,
                                                u64* __restrict__ suppr) {
#pragma clang fp contract(off)
    const int i = blockIdx.x;
    const int lane = threadIdx.x & 63;
    const int wv = threadIdx.x >> 6;
    const float4 bi = tb[i];
    const float ai = areas[i];
    for (int Wd = wv; Wd < RW; Wd += 4) {
        int j = Wd * 64 + lane;
        bool sup = false;
        if (j < KPRE) {
            float4 bj = tb[j];
            float iw = fmaxf(fminf(bi.z, bj.z) - fmaxf(bi.x, bj.x), 0.f);
            float ih = fmaxf(fminf(bi.w, bj.w) - fmaxf(bi.y, bj.y), 0.f);
            float inter = iw * ih;
            float denom = ((areas[j] + ai) - inter) + 1e-9f;
            sup = (inter / denom) > NMS_T;
        }
        u64 m = __ballot(sup);
        if (lane == 0) suppr[(size_t)i * RW + Wd] = m;
    }
}

/* ---------------- greedy scan over bitmap ---------------- */
__global__ void k_scan(const u64* __restrict__ suppr, int* __restrict__ keep) {
    const int lane = threadIdx.x; /* 64 threads */
    u64 a0 = (lane < 93) ? ~0ULL : (lane == 93 ? ((1ULL << 48) - 1) : 0ULL);
    const int w1 = lane + 64;
    u64 a1 = (w1 < 93) ? ~0ULL : (w1 == 93 ? ((1ULL << 48) - 1) : 0ULL);
    int kept = 0;
    int i = 0;
    while (kept < KPOST) {
        int wi = i >> 6;
        if (wi >= 94) break;
        u64 wvv = (wi < 64) ? __shfl(a0, wi) : __shfl(a1, wi - 64);
        wvv &= (~0ULL) << (i & 63);
        if (wvv == 0ULL) { i = (wi + 1) << 6; continue; }
        int b = __ffsll((long long)wvv) - 1;
        i = (wi << 6) + b;
        if (lane == 0) keep[kept] = i;
        kept++;
        const u64* row = suppr + (size_t)i * RW;
        u64 s0 = row[lane];
        u64 s1 = (lane + 64 < RW) ? row[lane + 64] : 0ULL;
        a0 &= ~s0;
        a1 &= ~s1;
        i++;
    }
}

/* ---------------- write rois ---------------- */
__global__ void k_rois(const int* __restrict__ keep, const float4* __restrict__ tb,
                       float* __restrict__ out) {
    int r = blockIdx.x * blockDim.x + threadIdx.x;
    if (r >= KPOST) return;
    int k = keep[r];
    float4 b = make_float4(0.f, 0.f, 0.f, 0.f);
    if (k >= 0) b = tb[k];
    out[r * 5 + 0] = 0.f;
    out[r * 5 + 1] = b.x;
    out[r * 5 + 2] = b.y;
    out[r * 5 + 3] = b.z;
    out[r * 5 + 4] = b.w;
}

extern "C" void kernel_launch(void* const* d_in, const int* in_sizes, int n_in,
                              void* d_out, int out_size, void* d_ws, size_t ws_size,
                              hipStream_t stream) {
    (void)in_sizes; (void)n_in; (void)out_size; (void)ws_size;
    const float* x     = (const float*)d_in[0];
    const float* meta  = (const float*)d_in[1];
    const float* wc3   = (const float*)d_in[3];
    const float* bc3   = (const float*)d_in[4];
    const float* wcls  = (const float*)d_in[5];
    const float* bcls  = (const float*)d_in[6];
    const float* wbox  = (const float*)d_in[7];
    const float* bboxb = (const float*)d_in[8];
    float* out = (float*)d_out;
    char* ws = (char*)d_ws;

    float*  conv1  = (float*)(ws + WS_CONV1);
    float*  wt     = (float*)(ws + WS_WT);
    float4* boxes  = (float4*)(ws + WS_BOXES);
    float*  scores = (float*)(ws + WS_SCORE);
    u64*    keys   = (u64*)(ws + WS_KEYS);
    float4* tb     = (float4*)(ws + WS_TB);
    float*  areas  = (float*)(ws + WS_AREA);
    u64*    suppr  = (u64*)(ws + WS_SUP);
    u32*    hist   = (u32*)(ws + WS_HIST);
    u32*    ctrl   = (u32*)(ws + WS_CTRL);
    int*    keep   = (int*)(ws + WS_KEEP);
    u64*    skeys  = (u64*)(ws + WS_SKEYS);

    k_wt<<<dim3(144, 8), 256, 0, stream>>>(wc3, wt);
    k_conv3<<<dim3(128, 4), 256, 0, stream>>>(x, wt, bc3, conv1);
    k_init<<<256, 256, 0, stream>>>(hist, ctrl, keep, keys);   /* after conv3: aliases wt */
    k_conv1<<<256, 256, 0, stream>>>(conv1, wcls, bcls, wbox, bboxb, out);
    k_decode<<<384, 256, 0, stream>>>(out, meta, boxes, scores);
    k_hist<<<384, 256, 0, stream>>>(scores, hist);
    k_select<<<1, 256, 0, stream>>>(hist, ctrl);
    k_compact<<<384, 256, 0, stream>>>(scores, ctrl, keys);
    k_sort_local<<<2, 1024, 0, stream>>>(keys);
    k_merge<<<24, 256, 0, stream>>>(keys, skeys);
    k_gather<<<24, 256, 0, stream>>>(skeys, boxes, tb, areas);
    k_bitmap<<<6000, 256, 0, stream>>>(tb, areas, suppr);
    k_scan<<<1, 64, 0, stream>>>(suppr, keep);
    k_rois<<<2, 256, 0, stream>>>(keep, tb, out);
}

// Round 5
// 2417.482 us; speedup vs baseline: 1.1008x; 1.0647x over previous
//
#include <hip/hip_runtime.h>
#include <math.h>

typedef unsigned int u32;
typedef unsigned long long u64;

#define HH 128
#define WW 128
#define NPIX (128*128)
#define NANCH (NPIX*6)
#define KPRE 6000
#define KPOST 300
#define SORT_CAP 16384
#define RW 96            /* u64 words per bitmap row */
#define NMS_T 0.7f

#define OUT_PROB 1500
#define OUT_BBOX (1500 + 98304)

/* ---------------- ws layout (bytes) ---------------- */
#define WS_CONV1 ((size_t)0)                     /* 512*16384*4 = 33554432 */
#define WS_WT    ((size_t)33554432)              /* 9216*512*4  = 18874368 */
#define WS_BOXES ((size_t)33554432)              /* aliases wt, post-conv3 */
#define WS_SCORE (WS_BOXES + 1572864)
#define WS_KEYS  (WS_SCORE + 393216)
#define WS_TB    (WS_KEYS + 131072)
#define WS_AREA  (WS_TB + 98304)
#define WS_SUP   (WS_AREA + 24576)
#define WS_HIST  (WS_SUP + 4718592)
#define WS_CTRL  (WS_HIST + 262144)
#define WS_KEEP  (WS_CTRL + 256)
#define WS_SKEYS (WS_KEEP + 1280)
/* total needed = 52428800 bytes */

/* row swizzle for X: involution within a 32-block (128-float) row */
__device__ __forceinline__ int swr(int b) { return b ^ ((b >> 3) & 1); }

/* async global->LDS, 16B per lane (gfx950). LDS dest must be wave-uniform. */
__device__ __forceinline__ void gl_lds16(const float* g, float* l) {
    __builtin_amdgcn_global_load_lds(
        (__attribute__((address_space(1))) const void*)g,
        (__attribute__((address_space(3))) void*)l,
        16, 0, 0);
}

/* ---------------- init (runs AFTER conv3; aliases wt region) ---------------- */
__global__ void k_init(u32* __restrict__ hist, u32* __restrict__ ctrl,
                       int* __restrict__ keep, u64* __restrict__ keys) {
    int t = blockIdx.x * blockDim.x + threadIdx.x;
    if (t < 65536) hist[t] = 0u;
    if (t < 64)    ctrl[t] = 0u;
    if (t < 304)   keep[t] = -1;
    if (t < SORT_CAP) keys[t] = ~0ULL;
}

/* ---------------- weight transpose + zero-stash ---------------- */
__global__ __launch_bounds__(256) void k_wt(const float* __restrict__ w,
                                            float* __restrict__ wt,
                                            float* __restrict__ zstash) {
    __shared__ float T[64][65];
    const int k0  = blockIdx.x * 64;   /* 144 blocks */
    const int oc0 = blockIdx.y * 64;   /* 8 blocks   */
    const int c = threadIdx.x & 63;
    const int r = threadIdx.x >> 6;
    if (blockIdx.x == 0 && blockIdx.y == 0 && threadIdx.x < 128)
        zstash[threadIdx.x] = 0.f;      /* 512B zero region for conv3 halo */
#pragma unroll
    for (int i = 0; i < 16; ++i) {
        int rr = r + i * 4;
        T[rr][c] = w[(size_t)(oc0 + rr) * 9216 + k0 + c];
    }
    __syncthreads();
#pragma unroll
    for (int i = 0; i < 16; ++i) {
        int rr = r + i * 4;
        wt[(size_t)(k0 + rr) * 512 + oc0 + c] = T[c][rr];
    }
}

/* ---------------- conv 3x3, 1024->512, pad 1, relu ----------------
   grid (128 rows, 4 oc-tiles), 256 thr. Block: 128 oc x 128 px row.
   Thread: 8 oc x 8 px. K-chunk = 4 input channels, 256 iterations.
   Staging: global_load_lds (async DMA, zero VGPR) into double-buffered
   LDS; loads for cc+1 issued right after the barrier -> in flight across
   the whole compute phase. X source is block-permuted so LDS reads are
   2-way max; image-edge rows redirect per-lane to a zero stash. */
__global__ __attribute__((amdgpu_flat_work_group_size(256, 256),
                          amdgpu_waves_per_eu(2, 2)))
void k_conv3(const float* __restrict__ in, const float* __restrict__ wt,
             const float* __restrict__ bias, const float* __restrict__ zero,
             float* __restrict__ out) {
    const int y   = blockIdx.x;
    const int oc0 = blockIdx.y * 128;
    const int tid = threadIdx.x;
    const int lane = tid & 63;
    const int wv   = tid >> 6;
    const int og  = tid >> 4;   /* 0..15 -> oc = oc0 + og*8 */
    const int pg  = tid & 15;   /* px = pg*8 */

    /* two buffers of 6144 floats: X [0,1536), W [1536,6144) */
    __shared__ __align__(16) float L[12288];

    /* ------ staging slot precompute: 6 DMA chunks (1KB each) per wave ------ */
    const float* gsrc[6];
    int          gstep[6];
    int          lof[6];        /* LDS float offset of chunk base (wave-uniform) */
#pragma unroll
    for (int i = 0; i < 6; ++i) {
        int k = wv + 4 * i;     /* 0..23: 0-5 = X chunks, 6-23 = W chunks */
        if (k < 6) {
            int p   = k * 64 + lane;        /* float4-block within X region */
            int c   = p / 96;
            int rem = p - c * 96;
            int dy  = rem >> 5;
            int q   = rem & 31;
            int bx  = swr(q);               /* source block within row */
            int yy  = y + dy - 1;
            bool ok = (yy >= 0 && yy < HH);
            gsrc[i]  = ok ? in + ((size_t)c * NPIX + yy * WW + bx * 4)
                          : zero + bx * 4;
            gstep[i] = ok ? 4 * NPIX : 0;
            lof[i]   = k * 256;
        } else {
            int p  = (k - 6) * 64 + lane;   /* float4-block within W region */
            int r  = p >> 5;
            int qw = p & 31;
            gsrc[i]  = wt + ((size_t)r * 512 + oc0 + qw * 4);
            gstep[i] = 36 * 512;
            lof[i]   = 1536 + (k - 6) * 256;
        }
    }

    auto issue = [&](int sel) {
#pragma unroll
        for (int i = 0; i < 6; ++i) {
            gl_lds16(gsrc[i], &L[lof[i] + sel * 6144]);
            gsrc[i] += gstep[i];
        }
    };

    /* ------ compute-side LDS read offsets (floats, within an X row) ------ */
    const int b0 = 2 * pg, b1 = 2 * pg + 1;
    const int bl = (2 * pg + 31) & 31, br = (2 * pg + 2) & 31;
    const int sA = swr(b0) * 4;
    const int sB = swr(b1) * 4;
    const int sL = swr(bl) * 4 + 3;
    const int sR = swr(br) * 4;
    const bool pz0 = (pg == 0), pz15 = (pg == 15);

    float acc[8][8];
#pragma unroll
    for (int o = 0; o < 8; ++o)
#pragma unroll
        for (int j = 0; j < 8; ++j) acc[o][j] = 0.f;

    issue(0);   /* preload cc=0 */

    for (int cc = 0; cc < 256; ++cc) {
        const int cur = cc & 1;
        __syncthreads();            /* drains cur-buffer loads (issued a full
                                       compute phase ago) + protects other buf */
        if (cc + 1 < 256) issue(cur ^ 1);

        const float* X0 = &L[cur * 6144];
        const float* W0 = &L[cur * 6144 + 1536];
#pragma unroll 1
        for (int cp = 0; cp < 4; ++cp) {
            float v[3][10];
#pragma unroll
            for (int dy = 0; dy < 3; ++dy) {
                const float* xr = X0 + cp * 384 + dy * 128;
                float4 pa = *(const float4*)(xr + sA);
                float4 pb = *(const float4*)(xr + sB);
                float lf = xr[sL];
                float rt = xr[sR];
                v[dy][0] = pz0 ? 0.f : lf;
                v[dy][1] = pa.x; v[dy][2] = pa.y; v[dy][3] = pa.z; v[dy][4] = pa.w;
                v[dy][5] = pb.x; v[dy][6] = pb.y; v[dy][7] = pb.z; v[dy][8] = pb.w;
                v[dy][9] = pz15 ? 0.f : rt;
            }
#pragma unroll
            for (int rr = 0; rr < 9; ++rr) {
                const int dy = rr / 3, dx = rr % 3;
                const float* wp = W0 + (cp * 9 + rr) * 128 + og * 8;
                const float4 w0 = *(const float4*)wp;
                const float4 w1 = *(const float4*)(wp + 4);
#pragma unroll
                for (int j = 0; j < 8; ++j) {
                    const float xv = v[dy][j + dx];
                    acc[0][j] = fmaf(w0.x, xv, acc[0][j]);
                    acc[1][j] = fmaf(w0.y, xv, acc[1][j]);
                    acc[2][j] = fmaf(w0.z, xv, acc[2][j]);
                    acc[3][j] = fmaf(w0.w, xv, acc[3][j]);
                    acc[4][j] = fmaf(w1.x, xv, acc[4][j]);
                    acc[5][j] = fmaf(w1.y, xv, acc[5][j]);
                    acc[6][j] = fmaf(w1.z, xv, acc[6][j]);
                    acc[7][j] = fmaf(w1.w, xv, acc[7][j]);
                }
            }
        }
    }
#pragma unroll
    for (int o = 0; o < 8; ++o) {
        const int oc = oc0 + og * 8 + o;
        const float b = bias[oc];
        float4 r0, r1;
        r0.x = fmaxf(acc[o][0] + b, 0.f);
        r0.y = fmaxf(acc[o][1] + b, 0.f);
        r0.z = fmaxf(acc[o][2] + b, 0.f);
        r0.w = fmaxf(acc[o][3] + b, 0.f);
        r1.x = fmaxf(acc[o][4] + b, 0.f);
        r1.y = fmaxf(acc[o][5] + b, 0.f);
        r1.z = fmaxf(acc[o][6] + b, 0.f);
        r1.w = fmaxf(acc[o][7] + b, 0.f);
        float* op = &out[(size_t)oc * NPIX + y * WW + pg * 8];
        *(float4*)op = r0;
        *(float4*)(op + 4) = r1;
    }
}

/* ---------------- fused 1x1 convs (cls 6 + bbox 24) + pair softmax ---------------- */
__global__ __launch_bounds__(256) void k_conv1(const float* __restrict__ conv1,
                                               const float* __restrict__ wcls,
                                               const float* __restrict__ bcls,
                                               const float* __restrict__ wbox,
                                               const float* __restrict__ bboxb,
                                               float* __restrict__ out) {
    const int tid = threadIdx.x;
    const int og = tid >> 4, pg = tid & 15;
    const int px0 = blockIdx.x * 64;
    __shared__ __align__(16) float Wl[32][32];
    __shared__ __align__(16) float Xl[32][64];
    __shared__ float Sc[6][64];

    float a0[4] = {0, 0, 0, 0}, a1[4] = {0, 0, 0, 0};

    for (int cc = 0; cc < 16; ++cc) {
        {
            int u = tid;
            int row = (u * 4) >> 5;
            int col = (u * 4) & 31;
            float4 v;
            if (row < 6)       v = *(const float4*)(wcls + row * 512 + cc * 32 + col);
            else if (row < 30) v = *(const float4*)(wbox + (row - 6) * 512 + cc * 32 + col);
            else               v = make_float4(0.f, 0.f, 0.f, 0.f);
            *(float4*)&Wl[row][col] = v;
        }
        for (int u = tid; u < 512; u += 256) {
            int row = (u * 4) >> 6, col = (u * 4) & 63;
            *(float4*)&Xl[row][col] =
                *(const float4*)(conv1 + (size_t)(cc * 32 + row) * NPIX + px0 + col);
        }
        __syncthreads();
#pragma unroll
        for (int cp = 0; cp < 32; ++cp) {
            const float4 x = *(const float4*)&Xl[cp][pg * 4];
            const float w0 = Wl[og][cp];
            const float w1 = Wl[og + 16][cp];
            a0[0] = fmaf(w0, x.x, a0[0]); a0[1] = fmaf(w0, x.y, a0[1]);
            a0[2] = fmaf(w0, x.z, a0[2]); a0[3] = fmaf(w0, x.w, a0[3]);
            a1[0] = fmaf(w1, x.x, a1[0]); a1[1] = fmaf(w1, x.y, a1[1]);
            a1[2] = fmaf(w1, x.z, a1[2]); a1[3] = fmaf(w1, x.w, a1[3]);
        }
        __syncthreads();
    }
    const int pxb = px0 + pg * 4;
    if (og < 6) {
        const float bc = bcls[og];
#pragma unroll
        for (int kk = 0; kk < 4; ++kk) Sc[og][pg * 4 + kk] = a0[kk] + bc;
    } else {
        const float bb = bboxb[og - 6];
#pragma unroll
        for (int kk = 0; kk < 4; ++kk)
            out[OUT_BBOX + (size_t)(og - 6) * NPIX + pxb + kk] = a0[kk] + bb;
    }
    if (og + 16 < 30) {
        const float bb = bboxb[og + 10];
#pragma unroll
        for (int kk = 0; kk < 4; ++kk)
            out[OUT_BBOX + (size_t)(og + 10) * NPIX + pxb + kk] = a1[kk] + bb;
    }
    __syncthreads();
    if (og < 6) {
        const int pa = og < 3 ? og + 3 : og - 3;
#pragma unroll
        for (int kk = 0; kk < 4; ++kk) {
            const float s = Sc[og][pg * 4 + kk], sp = Sc[pa][pg * 4 + kk];
            out[OUT_PROB + (size_t)og * NPIX + pxb + kk] = 1.0f / (1.0f + expf(sp - s));
        }
    }
}

/* ---------------- anchor decode + clip ---------------- */
__global__ void k_decode(const float* __restrict__ out, const float* __restrict__ meta,
                         float4* __restrict__ boxes, float* __restrict__ scores) {
#pragma clang fp contract(off)
    int t = blockIdx.x * blockDim.x + threadIdx.x;
    if (t >= NANCH) return;
    int a = t >> 14;
    int pix = t & 16383;
    int yc = pix >> 7, xc = pix & 127;
    int n = pix * 6 + a;
    float sc = out[OUT_PROB + (size_t)a * NPIX + pix];
    float d0 = out[OUT_BBOX + (size_t)(a * 4 + 0) * NPIX + pix];
    float d1 = out[OUT_BBOX + (size_t)(a * 4 + 1) * NPIX + pix];
    float d2 = out[OUT_BBOX + (size_t)(a * 4 + 2) * NPIX + pix];
    float d3 = out[OUT_BBOX + (size_t)(a * 4 + 3) * NPIX + pix];
    const float dims = (float)(16 << a);
    const float cxa = (xc + 0.5f) * 16.f;
    const float cya = (yc + 0.5f) * 16.f;
    float pcx = d0 * dims + cxa;
    float pcy = d1 * dims + cya;
    float pw  = expf(d2) * dims;
    float ph  = expf(d3) * dims;
    float imh = meta[0], imw = meta[1];
    float x1 = fminf(fmaxf(pcx - 0.5f * pw, 0.f), imw);
    float y1 = fminf(fmaxf(pcy - 0.5f * ph, 0.f), imh);
    float x2 = fminf(fmaxf(pcx + 0.5f * pw, 0.f), imw);
    float y2 = fminf(fmaxf(pcy + 0.5f * ph, 0.f), imh);
    boxes[n] = make_float4(x1, y1, x2, y2);
    scores[n] = sc;
}

/* ---------------- histogram on top-16 bits of score ---------------- */
__global__ void k_hist(const float* __restrict__ scores, u32* __restrict__ hist) {
    int t = blockIdx.x * blockDim.x + threadIdx.x;
    if (t >= NANCH) return;
    u32 b = __float_as_uint(scores[t]) >> 16;
    atomicAdd(&hist[b], 1u);
}

/* ---------------- find threshold bin (6000th largest) ---------------- */
__global__ void k_select(const u32* __restrict__ hist, u32* __restrict__ ctrl) {
    __shared__ u32 S[256];
    __shared__ u32 U[256];
    const int tid = threadIdx.x;
    u32 s = 0;
    for (int i = 0; i < 256; ++i) s += hist[tid * 256 + i];
    S[tid] = s;
    __syncthreads();
    if (tid == 0) {
        u32 acc = 0;
        for (int t = 255; t >= 0; --t) { U[t] = acc; acc += S[t]; }
    }
    __syncthreads();
    if (U[tid] < KPRE && U[tid] + S[tid] >= KPRE) {
        u32 acc = U[tid];
        for (int b = tid * 256 + 255; b >= tid * 256; --b) {
            u32 h = hist[b];
            if (acc + h >= KPRE) { ctrl[1] = (u32)b; ctrl[2] = acc; break; }
            acc += h;
        }
    }
}

/* ---------------- compact candidates ---------------- */
__global__ void k_compact(const float* __restrict__ scores, u32* __restrict__ ctrl,
                          u64* __restrict__ keys) {
    int t = blockIdx.x * blockDim.x + threadIdx.x;
    if (t >= NANCH) return;
    u32 bits = __float_as_uint(scores[t]);
    if ((bits >> 16) >= ctrl[1]) {
        u32 pos = atomicAdd(&ctrl[0], 1u);
        if (pos < SORT_CAP) keys[pos] = ((u64)(~bits) << 32) | (u32)t;
    }
}

/* ---------------- bitonic sort of 8192-key chunk in LDS ---------------- */
__global__ __launch_bounds__(1024) void k_sort_local(u64* __restrict__ keys) {
    __shared__ u64 lds[8192];
    const int tid = threadIdx.x;
    u64* g = keys + blockIdx.x * 8192;
    for (int u = tid; u < 8192; u += 1024) lds[u] = g[u];
    __syncthreads();
    for (int k = 2; k <= 8192; k <<= 1) {
        for (int j = k >> 1; j > 0; j >>= 1) {
            for (int u = tid; u < 4096; u += 1024) {
                int i = ((u & ~(j - 1)) << 1) | (u & (j - 1));
                int l = i | j;
                bool up = (i & k) == 0;
                u64 x = lds[i], y2 = lds[l];
                if ((x > y2) == up) { lds[i] = y2; lds[l] = x; }
            }
            __syncthreads();
        }
    }
    for (int u = tid; u < 8192; u += 1024) g[u] = lds[u];
}

/* ---------------- merge-path: first 6000 of two sorted 8192 runs ---------------- */
__global__ void k_merge(const u64* __restrict__ keys, u64* __restrict__ skeys) {
    int i = blockIdx.x * blockDim.x + threadIdx.x;
    if (i >= KPRE) return;
    const u64* A = keys;
    const u64* B = keys + 8192;
    int lo = i > 8192 ? i - 8192 : 0;
    int hi = i < 8192 ? i : 8192;
    while (lo < hi) {
        int a = (lo + hi) >> 1;
        if (A[a] < B[i - a - 1]) lo = a + 1; else hi = a;
    }
    int a = lo, b = i - lo;
    u64 va = (a < 8192) ? A[a] : ~0ULL;
    u64 vb = (b < 8192) ? B[b] : ~0ULL;
    skeys[i] = va < vb ? va : vb;
}

/* ---------------- gather top boxes + areas ---------------- */
__global__ void k_gather(const u64* __restrict__ skeys, const float4* __restrict__ boxes,
                         float4* __restrict__ tb, float* __restrict__ areas) {
#pragma clang fp contract(off)
    int i = blockIdx.x * blockDim.x + threadIdx.x;
    if (i >= KPRE) return;
    u32 n = (u32)(skeys[i] & 0xFFFFFFFFULL);
    float4 b = boxes[n];
    tb[i] = b;
    areas[i] = fmaxf(b.z - b.x, 0.f) * fmaxf(b.w - b.y, 0.f);
}

/* ---------------- suppression bitmap ---------------- */
__global__ __launch_bounds__(256) void k_bitmap(const float4* __restrict__ tb,
                                                const float* __restrict__ areas,
                                                u64* __restrict__ suppr) {
#pragma clang fp contract(off)
    const int i = blockIdx.x;
    const int lane = threadIdx.x & 63;
    const int wv = threadIdx.x >> 6;
    const float4 bi = tb[i];
    const float ai = areas[i];
    for (int Wd = wv; Wd < RW; Wd += 4) {
        int j = Wd * 64 + lane;
        bool sup = false;
        if (j < KPRE) {
            float4 bj = tb[j];
            float iw = fmaxf(fminf(bi.z, bj.z) - fmaxf(bi.x, bj.x), 0.f);
            float ih = fmaxf(fminf(bi.w, bj.w) - fmaxf(bi.y, bj.y), 0.f);
            float inter = iw * ih;
            float denom = ((areas[j] + ai) - inter) + 1e-9f;
            sup = (inter / denom) > NMS_T;
        }
        u64 m = __ballot(sup);
        if (lane == 0) suppr[(size_t)i * RW + Wd] = m;
    }
}

/* ---------------- greedy scan over bitmap ---------------- */
__global__ void k_scan(const u64* __restrict__ suppr, int* __restrict__ keep) {
    const int lane = threadIdx.x; /* 64 threads */
    u64 a0 = (lane < 93) ? ~0ULL : (lane == 93 ? ((1ULL << 48) - 1) : 0ULL);
    const int w1 = lane + 64;
    u64 a1 = (w1 < 93) ? ~0ULL : (w1 == 93 ? ((1ULL << 48) - 1) : 0ULL);
    int kept = 0;
    int i = 0;
    while (kept < KPOST) {
        int wi = i >> 6;
        if (wi >= 94) break;
        u64 wvv = (wi < 64) ? __shfl(a0, wi) : __shfl(a1, wi - 64);
        wvv &= (~0ULL) << (i & 63);
        if (wvv == 0ULL) { i = (wi + 1) << 6; continue; }
        int b = __ffsll((long long)wvv) - 1;
        i = (wi << 6) + b;
        if (lane == 0) keep[kept] = i;
        kept++;
        const u64* row = suppr + (size_t)i * RW;
        u64 s0 = row[lane];
        u64 s1 = (lane + 64 < RW) ? row[lane + 64] : 0ULL;
        a0 &= ~s0;
        a1 &= ~s1;
        i++;
    }
}

/* ---------------- write rois ---------------- */
__global__ void k_rois(const int* __restrict__ keep, const float4* __restrict__ tb,
                       float* __restrict__ out) {
    int r = blockIdx.x * blockDim.x + threadIdx.x;
    if (r >= KPOST) return;
    int k = keep[r];
    float4 b = make_float4(0.f, 0.f, 0.f, 0.f);
    if (k >= 0) b = tb[k];
    out[r * 5 + 0] = 0.f;
    out[r * 5 + 1] = b.x;
    out[r * 5 + 2] = b.y;
    out[r * 5 + 3] = b.z;
    out[r * 5 + 4] = b.w;
}

extern "C" void kernel_launch(void* const* d_in, const int* in_sizes, int n_in,
                              void* d_out, int out_size, void* d_ws, size_t ws_size,
                              hipStream_t stream) {
    (void)in_sizes; (void)n_in; (void)out_size; (void)ws_size;
    const float* x     = (const float*)d_in[0];
    const float* meta  = (const float*)d_in[1];
    const float* wc3   = (const float*)d_in[3];
    const float* bc3   = (const float*)d_in[4];
    const float* wcls  = (const float*)d_in[5];
    const float* bcls  = (const float*)d_in[6];
    const float* wbox  = (const float*)d_in[7];
    const float* bboxb = (const float*)d_in[8];
    float* out = (float*)d_out;
    char* ws = (char*)d_ws;

    float*  conv1  = (float*)(ws + WS_CONV1);
    float*  wt     = (float*)(ws + WS_WT);
    float4* boxes  = (float4*)(ws + WS_BOXES);
    float*  scores = (float*)(ws + WS_SCORE);
    u64*    keys   = (u64*)(ws + WS_KEYS);
    float4* tb     = (float4*)(ws + WS_TB);
    float*  areas  = (float*)(ws + WS_AREA);
    u64*    suppr  = (u64*)(ws + WS_SUP);
    u32*    hist   = (u32*)(ws + WS_HIST);
    u32*    ctrl   = (u32*)(ws + WS_CTRL);
    int*    keep   = (int*)(ws + WS_KEEP);
    u64*    skeys  = (u64*)(ws + WS_SKEYS);

    /* zero-stash lives in d_out's roi region (rewritten by k_rois at the end) */
    float*  zstash = out;

    k_wt<<<dim3(144, 8), 256, 0, stream>>>(wc3, wt, zstash);
    k_conv3<<<dim3(128, 4), 256, 0, stream>>>(x, wt, bc3, zstash, conv1);
    k_init<<<256, 256, 0, stream>>>(hist, ctrl, keep, keys);   /* after conv3: aliases wt */
    k_conv1<<<256, 256, 0, stream>>>(conv1, wcls, bcls, wbox, bboxb, out);
    k_decode<<<384, 256, 0, stream>>>(out, meta, boxes, scores);
    k_hist<<<384, 256, 0, stream>>>(scores, hist);
    k_select<<<1, 256, 0, stream>>>(hist, ctrl);
    k_compact<<<384, 256, 0, stream>>>(scores, ctrl, keys);
    k_sort_local<<<2, 1024, 0, stream>>>(keys);
    k_merge<<<24, 256, 0, stream>>>(keys, skeys);
    k_gather<<<24, 256, 0, stream>>>(skeys, boxes, tb, areas);
    k_bitmap<<<6000, 256, 0, stream>>>(tb, areas, suppr);
    k_scan<<<1, 64, 0, stream>>>(suppr, keep);
    k_rois<<<2, 256, 0, stream>>>(keep, tb, out);
}

// Round 6
// 1071.496 us; speedup vs baseline: 2.4835x; 2.2562x over previous
//
#include <hip/hip_runtime.h>
#include <math.h>

typedef unsigned int u32;
typedef unsigned long long u64;
typedef short s16x8 __attribute__((ext_vector_type(8)));
typedef float f32x4 __attribute__((ext_vector_type(4)));

#define HH 128
#define WW 128
#define NPIX (128*128)
#define NANCH (NPIX*6)
#define KPRE 6000
#define KPOST 300
#define SORT_CAP 16384
#define RW 96
#define NMS_T 0.7f

#define OUT_PROB 1500
#define OUT_BBOX (1500 + 98304)

/* ---------------- ws layout (bytes) ----------------
   big path : [conv1 33.5M][Xth 33.5M|Xtl 33.5M][Wph 9.4M|Wpl 9.4M] = 119.5MB
   small path (fallback, R5): [conv1][wt 18.9M]
   post-conv3 buffers alias offset 33.5MB in both paths. */
#define WS_CONV1 ((size_t)0)
#define WS_XTH   ((size_t)33554432)
#define WS_WPH   ((size_t)100663296)
#define WS_NEED_BIG ((size_t)119537664)
#define WS_WT    ((size_t)33554432)
#define WS_BOXES ((size_t)33554432)
#define WS_SCORE (WS_BOXES + 1572864)
#define WS_KEYS  (WS_SCORE + 393216)
#define WS_TB    (WS_KEYS + 131072)
#define WS_AREA  (WS_TB + 98304)
#define WS_SUP   (WS_AREA + 24576)
#define WS_HIST  (WS_SUP + 4718592)
#define WS_CTRL  (WS_HIST + 262144)
#define WS_KEEP  (WS_CTRL + 256)
#define WS_SKEYS (WS_KEEP + 1280)

__device__ __forceinline__ int swb(int b) { return b ^ ((b >> 4) & 1); }

__device__ __forceinline__ unsigned short f2bf(float x) {
    u32 b = __float_as_uint(x);
    u32 r = (b + 0x7FFFu + ((b >> 16) & 1u)) >> 16;
    return (unsigned short)r;
}

/* async global->LDS, 16B/lane: dest = wave-uniform base + lane*16 */
__device__ __forceinline__ void gl_lds16(const void* g, void* l) {
    __builtin_amdgcn_global_load_lds(
        (__attribute__((address_space(1))) const void*)g,
        (__attribute__((address_space(3))) void*)l,
        16, 0, 0);
}

/* ---------------- init (after conv3; aliases staging region) ---------------- */
__global__ void k_init(u32* __restrict__ hist, u32* __restrict__ ctrl,
                       int* __restrict__ keep, u64* __restrict__ keys) {
    int t = blockIdx.x * blockDim.x + threadIdx.x;
    if (t < 65536) hist[t] = 0u;
    if (t < 64)    ctrl[t] = 0u;
    if (t < 304)   keep[t] = -1;
    if (t < SORT_CAP) keys[t] = ~0ULL;
}

/* ================= BIG PATH: bf16 split-3 MFMA conv ================= */

/* X prepass: in[c][pix] f32 -> Xth[pix][c], Xtl[pix][c] bf16 (transpose+split) */
__global__ __launch_bounds__(256) void k_xsplit(const float* __restrict__ in,
                                                unsigned short* __restrict__ xth) {
    unsigned short* xtl = xth + 16777216;
    __shared__ unsigned short Th[64][72];
    __shared__ unsigned short Tl[64][72];
    const int px0 = blockIdx.x * 64;   /* 256 */
    const int c0  = blockIdx.y * 64;   /* 16  */
    const int t = threadIdx.x;
    const int r = t >> 4;
    const int p4 = (t & 15) * 4;
#pragma unroll
    for (int i = 0; i < 4; ++i) {
        int cr = r + 16 * i;
        float4 v = *(const float4*)(in + (size_t)(c0 + cr) * NPIX + px0 + p4);
        float vv[4] = {v.x, v.y, v.z, v.w};
#pragma unroll
        for (int k = 0; k < 4; ++k) {
            unsigned short h = f2bf(vv[k]);
            float hf = __uint_as_float((u32)h << 16);
            unsigned short l = f2bf(vv[k] - hf);
            Th[p4 + k][cr] = h;
            Tl[p4 + k][cr] = l;
        }
    }
    __syncthreads();
    const int p = t >> 2, q = t & 3;
    unsigned short* dh = xth + (size_t)(px0 + p) * 1024 + c0 + q * 16;
    unsigned short* dl = xtl + (size_t)(px0 + p) * 1024 + c0 + q * 16;
    *(uint4*)dh       = *(const uint4*)&Th[p][q * 16];
    *(uint4*)(dh + 8) = *(const uint4*)&Th[p][q * 16 + 8];
    *(uint4*)dl       = *(const uint4*)&Tl[p][q * 16];
    *(uint4*)(dl + 8) = *(const uint4*)&Tl[p][q * 16 + 8];
}

/* W prepass: w[oc][c*9+tap] -> Wph[tap][oc][c], Wpl[...] bf16; + zero-stash */
__global__ __launch_bounds__(256) void k_wpack(const float* __restrict__ w,
                                               unsigned short* __restrict__ wph,
                                               float* __restrict__ zstash) {
    if (blockIdx.x == 0 && threadIdx.x < 128) zstash[threadIdx.x] = 0.f;
    int id = blockIdx.x * 256 + threadIdx.x;     /* 524288 = oc*1024 + c */
    int oc = id >> 10, c = id & 1023;
    const float* src = w + (size_t)oc * 9216 + c * 9;
#pragma unroll
    for (int tap = 0; tap < 9; ++tap) {
        float x = src[tap];
        unsigned short h = f2bf(x);
        unsigned short l = f2bf(x - __uint_as_float((u32)h << 16));
        wph[(size_t)tap * 524288 + id] = h;
        wph[4718592 + (size_t)tap * 524288 + id] = l;
    }
}

/* conv3 via MFMA: block = 64oc x 64px (one row y), 4 waves (16oc x 64px each).
   dy-outer (skip OOB), per chunk: 32 channels, 3 dx taps, split-3 bf16.
   LDS: X [2pl][72 rows][32c] u16 = 9216B at 0; W [3dx][2pl][64oc][32c] = 24576B
   at 4608 (u16 idx); garbage pad to 18432 u16. Granule swizzle b^((row>>1)&3)
   applied on the DMA *source* so fragment ds_reads are 2-way (free). */
__global__ __launch_bounds__(256) void k_conv3m(const unsigned short* __restrict__ xt,
                                                const unsigned short* __restrict__ wp,
                                                const float* __restrict__ bias,
                                                const unsigned short* __restrict__ zst,
                                                float* __restrict__ out) {
    const int ocg = blockIdx.x;     /* 0..7  -> XCD key */
    const int y   = blockIdx.y;     /* 0..127 */
    const int xh  = blockIdx.z;     /* 0..1   */
    const int oc0 = ocg * 64;
    const int px0 = xh * 64;
    const int tid = threadIdx.x;
    const int lane = tid & 63;
    const int w    = tid >> 6;
    const int l15  = lane & 15;
    const int quad = lane >> 4;

    __shared__ __align__(16) unsigned short Lds[18432];

    const int ocr  = w * 16 + l15;
    const int aswz = ((quad ^ ((ocr >> 1) & 3)) << 3);

    f32x4 acc[4];
#pragma unroll
    for (int nt = 0; nt < 4; ++nt) acc[nt] = (f32x4){0.f, 0.f, 0.f, 0.f};

    for (int dy = 0; dy < 3; ++dy) {
        const int yy = y + dy - 1;
        if (yy < 0 || yy >= HH) continue;   /* zero-pad row: uniform skip */

        /* build 9 per-lane DMA sources for this dy (chunk c0=0) */
        const unsigned short* src[9];
        int step[9];
#pragma unroll
        for (int r = 0; r < 9; ++r) {
            int g = (r * 4 + w) * 64 + lane;
            const unsigned short* s;
            int st;
            if (g < 576) {                       /* X: [pl][row p][granule b] */
                int pl = g / 288, rem = g % 288;
                int p = rem >> 2, bst = rem & 3;
                int bsrc = bst ^ ((p >> 1) & 3);
                int gx = px0 - 1 + p;
                if (p < 66 && gx >= 0 && gx < WW) {
                    s = xt + pl * 16777216 + (size_t)(yy * WW + gx) * 1024 + bsrc * 8;
                    st = 32;
                } else { s = zst + (g & 3) * 8; st = 0; }
            } else if (g < 2112) {               /* W: [dx][pl][oc][granule] */
                int wg = g - 576;
                int dx = wg / 512, rem = wg % 512;
                int pl = rem / 256;
                int oc_r = (rem % 256) >> 2;
                int bst = rem & 3;
                int bsrc = bst ^ ((oc_r >> 1) & 3);
                int tap = dy * 3 + dx;
                s = wp + pl * 4718592 + (size_t)((tap * 512) + oc0 + oc_r) * 1024 + bsrc * 8;
                st = 32;
            } else { s = zst + (g & 3) * 8; st = 0; }
            src[r] = s;
            step[r] = st;
        }

        for (int cc = 0; cc < 32; ++cc) {
            __syncthreads();     /* prev compute done before overwrite */
#pragma unroll
            for (int r = 0; r < 9; ++r) {
                gl_lds16(src[r], &Lds[(r * 4 + w) * 512]);
                src[r] += step[r];
            }
            __syncthreads();     /* vmcnt(0) drain: staged data visible */

#pragma unroll
            for (int dx = 0; dx < 3; ++dx) {
                const s16x8 ah = *(const s16x8*)&Lds[4608 + (dx * 2 + 0) * 2048 + ocr * 32 + aswz];
                const s16x8 al = *(const s16x8*)&Lds[4608 + (dx * 2 + 1) * 2048 + ocr * 32 + aswz];
#pragma unroll
                for (int nt = 0; nt < 4; ++nt) {
                    const int p = nt * 16 + l15 + dx;
                    const int sw = ((quad ^ ((p >> 1) & 3)) << 3);
                    const s16x8 bh = *(const s16x8*)&Lds[p * 32 + sw];
                    const s16x8 bl = *(const s16x8*)&Lds[2304 + p * 32 + sw];
                    acc[nt] = __builtin_amdgcn_mfma_f32_16x16x32_bf16(ah, bh, acc[nt], 0, 0, 0);
                    acc[nt] = __builtin_amdgcn_mfma_f32_16x16x32_bf16(ah, bl, acc[nt], 0, 0, 0);
                    acc[nt] = __builtin_amdgcn_mfma_f32_16x16x32_bf16(al, bh, acc[nt], 0, 0, 0);
                }
            }
        }
    }

    /* epilogue: D row = quad*4+reg (oc), col = l15 (px) */
#pragma unroll
    for (int nt = 0; nt < 4; ++nt) {
#pragma unroll
        for (int rg = 0; rg < 4; ++rg) {
            const int oc = oc0 + w * 16 + quad * 4 + rg;
            const int px = px0 + nt * 16 + l15;
            float v = acc[nt][rg] + bias[oc];
            out[(size_t)oc * NPIX + y * WW + px] = fmaxf(v, 0.f);
        }
    }
}

/* ================= SMALL PATH (fallback): R5 fp32 conv ================= */

__global__ __launch_bounds__(256) void k_wt(const float* __restrict__ w,
                                            float* __restrict__ wt,
                                            float* __restrict__ zstash) {
    __shared__ float T[64][65];
    const int k0  = blockIdx.x * 64;
    const int oc0 = blockIdx.y * 64;
    const int c = threadIdx.x & 63;
    const int r = threadIdx.x >> 6;
    if (blockIdx.x == 0 && blockIdx.y == 0 && threadIdx.x < 128)
        zstash[threadIdx.x] = 0.f;
#pragma unroll
    for (int i = 0; i < 16; ++i) {
        int rr = r + i * 4;
        T[rr][c] = w[(size_t)(oc0 + rr) * 9216 + k0 + c];
    }
    __syncthreads();
#pragma unroll
    for (int i = 0; i < 16; ++i) {
        int rr = r + i * 4;
        wt[(size_t)(k0 + rr) * 512 + oc0 + c] = T[c][rr];
    }
}

__device__ __forceinline__ int swr(int b) { return b ^ ((b >> 3) & 1); }

__global__ __attribute__((amdgpu_flat_work_group_size(256, 256),
                          amdgpu_waves_per_eu(2, 2)))
void k_conv3(const float* __restrict__ in, const float* __restrict__ wt,
             const float* __restrict__ bias, const float* __restrict__ zero,
             float* __restrict__ out) {
    const int y   = blockIdx.x;
    const int oc0 = blockIdx.y * 128;
    const int tid = threadIdx.x;
    const int lane = tid & 63;
    const int wv   = tid >> 6;
    const int og  = tid >> 4;
    const int pg  = tid & 15;

    __shared__ __align__(16) float L[12288];

    const float* gsrc[6];
    int          gstep[6];
    int          lof[6];
#pragma unroll
    for (int i = 0; i < 6; ++i) {
        int k = wv + 4 * i;
        if (k < 6) {
            int p   = k * 64 + lane;
            int c   = p / 96;
            int rem = p - c * 96;
            int dy  = rem >> 5;
            int q   = rem & 31;
            int bx  = swr(q);
            int yy  = y + dy - 1;
            bool ok = (yy >= 0 && yy < HH);
            gsrc[i]  = ok ? in + ((size_t)c * NPIX + yy * WW + bx * 4)
                          : zero + bx * 4;
            gstep[i] = ok ? 4 * NPIX : 0;
            lof[i]   = k * 256;
        } else {
            int p  = (k - 6) * 64 + lane;
            int r  = p >> 5;
            int qw = p & 31;
            gsrc[i]  = wt + ((size_t)r * 512 + oc0 + qw * 4);
            gstep[i] = 36 * 512;
            lof[i]   = 1536 + (k - 6) * 256;
        }
    }

    auto issue = [&](int sel) {
#pragma unroll
        for (int i = 0; i < 6; ++i) {
            gl_lds16(gsrc[i], &L[lof[i] + sel * 6144]);
            gsrc[i] += gstep[i];
        }
    };

    const int b0 = 2 * pg, b1 = 2 * pg + 1;
    const int bl = (2 * pg + 31) & 31, br = (2 * pg + 2) & 31;
    const int sA = swr(b0) * 4;
    const int sB = swr(b1) * 4;
    const int sL = swr(bl) * 4 + 3;
    const int sR = swr(br) * 4;
    const bool pz0 = (pg == 0), pz15 = (pg == 15);

    float acc[8][8];
#pragma unroll
    for (int o = 0; o < 8; ++o)
#pragma unroll
        for (int j = 0; j < 8; ++j) acc[o][j] = 0.f;

    issue(0);

    for (int cc = 0; cc < 256; ++cc) {
        const int cur = cc & 1;
        __syncthreads();
        if (cc + 1 < 256) issue(cur ^ 1);

        const float* X0 = &L[cur * 6144];
        const float* W0 = &L[cur * 6144 + 1536];
#pragma unroll 1
        for (int cp = 0; cp < 4; ++cp) {
            float v[3][10];
#pragma unroll
            for (int dy = 0; dy < 3; ++dy) {
                const float* xr = X0 + cp * 384 + dy * 128;
                float4 pa = *(const float4*)(xr + sA);
                float4 pb = *(const float4*)(xr + sB);
                float lf = xr[sL];
                float rt = xr[sR];
                v[dy][0] = pz0 ? 0.f : lf;
                v[dy][1] = pa.x; v[dy][2] = pa.y; v[dy][3] = pa.z; v[dy][4] = pa.w;
                v[dy][5] = pb.x; v[dy][6] = pb.y; v[dy][7] = pb.z; v[dy][8] = pb.w;
                v[dy][9] = pz15 ? 0.f : rt;
            }
#pragma unroll
            for (int rr = 0; rr < 9; ++rr) {
                const int dy = rr / 3, dx = rr % 3;
                const float* wpt = W0 + (cp * 9 + rr) * 128 + og * 8;
                const float4 w0 = *(const float4*)wpt;
                const float4 w1 = *(const float4*)(wpt + 4);
#pragma unroll
                for (int j = 0; j < 8; ++j) {
                    const float xv = v[dy][j + dx];
                    acc[0][j] = fmaf(w0.x, xv, acc[0][j]);
                    acc[1][j] = fmaf(w0.y, xv, acc[1][j]);
                    acc[2][j] = fmaf(w0.z, xv, acc[2][j]);
                    acc[3][j] = fmaf(w0.w, xv, acc[3][j]);
                    acc[4][j] = fmaf(w1.x, xv, acc[4][j]);
                    acc[5][j] = fmaf(w1.y, xv, acc[5][j]);
                    acc[6][j] = fmaf(w1.z, xv, acc[6][j]);
                    acc[7][j] = fmaf(w1.w, xv, acc[7][j]);
                }
            }
        }
    }
#pragma unroll
    for (int o = 0; o < 8; ++o) {
        const int oc = oc0 + og * 8 + o;
        const float b = bias[oc];
        float4 r0, r1;
        r0.x = fmaxf(acc[o][0] + b, 0.f);
        r0.y = fmaxf(acc[o][1] + b, 0.f);
        r0.z = fmaxf(acc[o][2] + b, 0.f);
        r0.w = fmaxf(acc[o][3] + b, 0.f);
        r1.x = fmaxf(acc[o][4] + b, 0.f);
        r1.y = fmaxf(acc[o][5] + b, 0.f);
        r1.z = fmaxf(acc[o][6] + b, 0.f);
        r1.w = fmaxf(acc[o][7] + b, 0.f);
        float* op = &out[(size_t)oc * NPIX + y * WW + pg * 8];
        *(float4*)op = r0;
        *(float4*)(op + 4) = r1;
    }
}

/* ---------------- fused 1x1 convs + pair softmax ---------------- */
__global__ __launch_bounds__(256) void k_conv1(const float* __restrict__ conv1,
                                               const float* __restrict__ wcls,
                                               const float* __restrict__ bcls,
                                               const float* __restrict__ wbox,
                                               const float* __restrict__ bboxb,
                                               float* __restrict__ out) {
    const int tid = threadIdx.x;
    const int og = tid >> 4, pg = tid & 15;
    const int px0 = blockIdx.x * 64;
    __shared__ __align__(16) float Wl[32][32];
    __shared__ __align__(16) float Xl[32][64];
    __shared__ float Sc[6][64];

    float a0[4] = {0, 0, 0, 0}, a1[4] = {0, 0, 0, 0};

    for (int cc = 0; cc < 16; ++cc) {
        {
            int u = tid;
            int row = (u * 4) >> 5;
            int col = (u * 4) & 31;
            float4 v;
            if (row < 6)       v = *(const float4*)(wcls + row * 512 + cc * 32 + col);
            else if (row < 30) v = *(const float4*)(wbox + (row - 6) * 512 + cc * 32 + col);
            else               v = make_float4(0.f, 0.f, 0.f, 0.f);
            *(float4*)&Wl[row][col] = v;
        }
        for (int u = tid; u < 512; u += 256) {
            int row = (u * 4) >> 6, col = (u * 4) & 63;
            *(float4*)&Xl[row][col] =
                *(const float4*)(conv1 + (size_t)(cc * 32 + row) * NPIX + px0 + col);
        }
        __syncthreads();
#pragma unroll
        for (int cp = 0; cp < 32; ++cp) {
            const float4 x = *(const float4*)&Xl[cp][pg * 4];
            const float w0 = Wl[og][cp];
            const float w1 = Wl[og + 16][cp];
            a0[0] = fmaf(w0, x.x, a0[0]); a0[1] = fmaf(w0, x.y, a0[1]);
            a0[2] = fmaf(w0, x.z, a0[2]); a0[3] = fmaf(w0, x.w, a0[3]);
            a1[0] = fmaf(w1, x.x, a1[0]); a1[1] = fmaf(w1, x.y, a1[1]);
            a1[2] = fmaf(w1, x.z, a1[2]); a1[3] = fmaf(w1, x.w, a1[3]);
        }
        __syncthreads();
    }
    const int pxb = px0 + pg * 4;
    if (og < 6) {
        const float bc = bcls[og];
#pragma unroll
        for (int kk = 0; kk < 4; ++kk) Sc[og][pg * 4 + kk] = a0[kk] + bc;
    } else {
        const float bb = bboxb[og - 6];
#pragma unroll
        for (int kk = 0; kk < 4; ++kk)
            out[OUT_BBOX + (size_t)(og - 6) * NPIX + pxb + kk] = a0[kk] + bb;
    }
    if (og + 16 < 30) {
        const float bb = bboxb[og + 10];
#pragma unroll
        for (int kk = 0; kk < 4; ++kk)
            out[OUT_BBOX + (size_t)(og + 10) * NPIX + pxb + kk] = a1[kk] + bb;
    }
    __syncthreads();
    if (og < 6) {
        const int pa = og < 3 ? og + 3 : og - 3;
#pragma unroll
        for (int kk = 0; kk < 4; ++kk) {
            const float s = Sc[og][pg * 4 + kk], sp = Sc[pa][pg * 4 + kk];
            out[OUT_PROB + (size_t)og * NPIX + pxb + kk] = 1.0f / (1.0f + expf(sp - s));
        }
    }
}

/* ---------------- anchor decode + clip ---------------- */
__global__ void k_decode(const float* __restrict__ out, const float* __restrict__ meta,
                         float4* __restrict__ boxes, float* __restrict__ scores) {
#pragma clang fp contract(off)
    int t = blockIdx.x * blockDim.x + threadIdx.x;
    if (t >= NANCH) return;
    int a = t >> 14;
    int pix = t & 16383;
    int yc = pix >> 7, xc = pix & 127;
    int n = pix * 6 + a;
    float sc = out[OUT_PROB + (size_t)a * NPIX + pix];
    float d0 = out[OUT_BBOX + (size_t)(a * 4 + 0) * NPIX + pix];
    float d1 = out[OUT_BBOX + (size_t)(a * 4 + 1) * NPIX + pix];
    float d2 = out[OUT_BBOX + (size_t)(a * 4 + 2) * NPIX + pix];
    float d3 = out[OUT_BBOX + (size_t)(a * 4 + 3) * NPIX + pix];
    const float dims = (float)(16 << a);
    const float cxa = (xc + 0.5f) * 16.f;
    const float cya = (yc + 0.5f) * 16.f;
    float pcx = d0 * dims + cxa;
    float pcy = d1 * dims + cya;
    float pw  = expf(d2) * dims;
    float ph  = expf(d3) * dims;
    float imh = meta[0], imw = meta[1];
    float x1 = fminf(fmaxf(pcx - 0.5f * pw, 0.f), imw);
    float y1 = fminf(fmaxf(pcy - 0.5f * ph, 0.f), imh);
    float x2 = fminf(fmaxf(pcx + 0.5f * pw, 0.f), imw);
    float y2 = fminf(fmaxf(pcy + 0.5f * ph, 0.f), imh);
    boxes[n] = make_float4(x1, y1, x2, y2);
    scores[n] = sc;
}

__global__ void k_hist(const float* __restrict__ scores, u32* __restrict__ hist) {
    int t = blockIdx.x * blockDim.x + threadIdx.x;
    if (t >= NANCH) return;
    u32 b = __float_as_uint(scores[t]) >> 16;
    atomicAdd(&hist[b], 1u);
}

__global__ void k_select(const u32* __restrict__ hist, u32* __restrict__ ctrl) {
    __shared__ u32 S[256];
    __shared__ u32 U[256];
    const int tid = threadIdx.x;
    u32 s = 0;
    for (int i = 0; i < 256; ++i) s += hist[tid * 256 + i];
    S[tid] = s;
    __syncthreads();
    if (tid == 0) {
        u32 acc = 0;
        for (int t2 = 255; t2 >= 0; --t2) { U[t2] = acc; acc += S[t2]; }
    }
    __syncthreads();
    if (U[tid] < KPRE && U[tid] + S[tid] >= KPRE) {
        u32 acc = U[tid];
        for (int b = tid * 256 + 255; b >= tid * 256; --b) {
            u32 h = hist[b];
            if (acc + h >= KPRE) { ctrl[1] = (u32)b; ctrl[2] = acc; break; }
            acc += h;
        }
    }
}

__global__ void k_compact(const float* __restrict__ scores, u32* __restrict__ ctrl,
                          u64* __restrict__ keys) {
    int t = blockIdx.x * blockDim.x + threadIdx.x;
    if (t >= NANCH) return;
    u32 bits = __float_as_uint(scores[t]);
    if ((bits >> 16) >= ctrl[1]) {
        u32 pos = atomicAdd(&ctrl[0], 1u);
        if (pos < SORT_CAP) keys[pos] = ((u64)(~bits) << 32) | (u32)t;
    }
}

__global__ __launch_bounds__(1024) void k_sort_local(u64* __restrict__ keys) {
    __shared__ u64 lds[8192];
    const int tid = threadIdx.x;
    u64* g = keys + blockIdx.x * 8192;
    for (int u = tid; u < 8192; u += 1024) lds[u] = g[u];
    __syncthreads();
    for (int k = 2; k <= 8192; k <<= 1) {
        for (int j = k >> 1; j > 0; j >>= 1) {
            for (int u = tid; u < 4096; u += 1024) {
                int i = ((u & ~(j - 1)) << 1) | (u & (j - 1));
                int l = i | j;
                bool up = (i & k) == 0;
                u64 x = lds[i], y2 = lds[l];
                if ((x > y2) == up) { lds[i] = y2; lds[l] = x; }
            }
            __syncthreads();
        }
    }
    for (int u = tid; u < 8192; u += 1024) g[u] = lds[u];
}

__global__ void k_merge(const u64* __restrict__ keys, u64* __restrict__ skeys) {
    int i = blockIdx.x * blockDim.x + threadIdx.x;
    if (i >= KPRE) return;
    const u64* A = keys;
    const u64* B = keys + 8192;
    int lo = i > 8192 ? i - 8192 : 0;
    int hi = i < 8192 ? i : 8192;
    while (lo < hi) {
        int a = (lo + hi) >> 1;
        if (A[a] < B[i - a - 1]) lo = a + 1; else hi = a;
    }
    int a = lo, b = i - lo;
    u64 va = (a < 8192) ? A[a] : ~0ULL;
    u64 vb = (b < 8192) ? B[b] : ~0ULL;
    skeys[i] = va < vb ? va : vb;
}

__global__ void k_gather(const u64* __restrict__ skeys, const float4* __restrict__ boxes,
                         float4* __restrict__ tb, float* __restrict__ areas) {
#pragma clang fp contract(off)
    int i = blockIdx.x * blockDim.x + threadIdx.x;
    if (i >= KPRE) return;
    u32 n = (u32)(skeys[i] & 0xFFFFFFFFULL);
    float4 b = boxes[n];
    tb[i] = b;
    areas[i] = fmaxf(b.z - b.x, 0.f) * fmaxf(b.w - b.y, 0.f);
}

__global__ __launch_bounds__(256) void k_bitmap(const float4* __restrict__ tb,
                                                const float* __restrict__ areas,
                                                u64* __restrict__ suppr) {
#pragma clang fp contract(off)
    const int i = blockIdx.x;
    const int lane = threadIdx.x & 63;
    const int wv = threadIdx.x >> 6;
    const float4 bi = tb[i];
    const float ai = areas[i];
    for (int Wd = wv; Wd < RW; Wd += 4) {
        int j = Wd * 64 + lane;
        bool sup = false;
        if (j < KPRE) {
            float4 bj = tb[j];
            float iw = fmaxf(fminf(bi.z, bj.z) - fmaxf(bi.x, bj.x), 0.f);
            float ih = fmaxf(fminf(bi.w, bj.w) - fmaxf(bi.y, bj.y), 0.f);
            float inter = iw * ih;
            float denom = ((areas[j] + ai) - inter) + 1e-9f;
            sup = (inter / denom) > NMS_T;
        }
        u64 m = __ballot(sup);
        if (lane == 0) suppr[(size_t)i * RW + Wd] = m;
    }
}

__global__ void k_scan(const u64* __restrict__ suppr, int* __restrict__ keep) {
    const int lane = threadIdx.x;
    u64 a0 = (lane < 93) ? ~0ULL : (lane == 93 ? ((1ULL << 48) - 1) : 0ULL);
    const int w1 = lane + 64;
    u64 a1 = (w1 < 93) ? ~0ULL : (w1 == 93 ? ((1ULL << 48) - 1) : 0ULL);
    int kept = 0;
    int i = 0;
    while (kept < KPOST) {
        int wi = i >> 6;
        if (wi >= 94) break;
        u64 wvv = (wi < 64) ? __shfl(a0, wi) : __shfl(a1, wi - 64);
        wvv &= (~0ULL) << (i & 63);
        if (wvv == 0ULL) { i = (wi + 1) << 6; continue; }
        int b = __ffsll((long long)wvv) - 1;
        i = (wi << 6) + b;
        if (lane == 0) keep[kept] = i;
        kept++;
        const u64* row = suppr + (size_t)i * RW;
        u64 s0 = row[lane];
        u64 s1 = (lane + 64 < RW) ? row[lane + 64] : 0ULL;
        a0 &= ~s0;
        a1 &= ~s1;
        i++;
    }
}

__global__ void k_rois(const int* __restrict__ keep, const float4* __restrict__ tb,
                       float* __restrict__ out) {
    int r = blockIdx.x * blockDim.x + threadIdx.x;
    if (r >= KPOST) return;
    int k = keep[r];
    float4 b = make_float4(0.f, 0.f, 0.f, 0.f);
    if (k >= 0) b = tb[k];
    out[r * 5 + 0] = 0.f;
    out[r * 5 + 1] = b.x;
    out[r * 5 + 2] = b.y;
    out[r * 5 + 3] = b.z;
    out[r * 5 + 4] = b.w;
}

extern "C" void kernel_launch(void* const* d_in, const int* in_sizes, int n_in,
                              void* d_out, int out_size, void* d_ws, size_t ws_size,
                              hipStream_t stream) {
    (void)in_sizes; (void)n_in; (void)out_size;
    const float* x     = (const float*)d_in[0];
    const float* meta  = (const float*)d_in[1];
    const float* wc3   = (const float*)d_in[3];
    const float* bc3   = (const float*)d_in[4];
    const float* wcls  = (const float*)d_in[5];
    const float* bcls  = (const float*)d_in[6];
    const float* wbox  = (const float*)d_in[7];
    const float* bboxb = (const float*)d_in[8];
    float* out = (float*)d_out;
    char* ws = (char*)d_ws;

    float*  conv1  = (float*)(ws + WS_CONV1);
    float4* boxes  = (float4*)(ws + WS_BOXES);
    float*  scores = (float*)(ws + WS_SCORE);
    u64*    keys   = (u64*)(ws + WS_KEYS);
    float4* tb     = (float4*)(ws + WS_TB);
    float*  areas  = (float*)(ws + WS_AREA);
    u64*    suppr  = (u64*)(ws + WS_SUP);
    u32*    hist   = (u32*)(ws + WS_HIST);
    u32*    ctrl   = (u32*)(ws + WS_CTRL);
    int*    keep   = (int*)(ws + WS_KEEP);
    u64*    skeys  = (u64*)(ws + WS_SKEYS);

    float* zstash = out;   /* 512B zeros; rewritten by k_rois at the end */

    if (ws_size >= WS_NEED_BIG) {
        unsigned short* xth = (unsigned short*)(ws + WS_XTH);
        unsigned short* wph = (unsigned short*)(ws + WS_WPH);
        k_xsplit<<<dim3(256, 16), 256, 0, stream>>>(x, xth);
        k_wpack<<<2048, 256, 0, stream>>>(wc3, wph, zstash);
        k_conv3m<<<dim3(8, 128, 2), 256, 0, stream>>>(xth, wph, bc3,
                                                      (const unsigned short*)zstash, conv1);
    } else {
        float* wt = (float*)(ws + WS_WT);
        k_wt<<<dim3(144, 8), 256, 0, stream>>>(wc3, wt, zstash);
        k_conv3<<<dim3(128, 4), 256, 0, stream>>>(x, wt, bc3, zstash, conv1);
    }

    k_init<<<256, 256, 0, stream>>>(hist, ctrl, keep, keys);
    k_conv1<<<256, 256, 0, stream>>>(conv1, wcls, bcls, wbox, bboxb, out);
    k_decode<<<384, 256, 0, stream>>>(out, meta, boxes, scores);
    k_hist<<<384, 256, 0, stream>>>(scores, hist);
    k_select<<<1, 256, 0, stream>>>(hist, ctrl);
    k_compact<<<384, 256, 0, stream>>>(scores, ctrl, keys);
    k_sort_local<<<2, 1024, 0, stream>>>(keys);
    k_merge<<<24, 256, 0, stream>>>(keys, skeys);
    k_gather<<<24, 256, 0, stream>>>(skeys, boxes, tb, areas);
    k_bitmap<<<6000, 256, 0, stream>>>(tb, areas, suppr);
    k_scan<<<1, 64, 0, stream>>>(suppr, keep);
    k_rois<<<2, 256, 0, stream>>>(keep, tb, out);
}

// Round 7
// 928.140 us; speedup vs baseline: 2.8671x; 1.1545x over previous
//
#include <hip/hip_runtime.h>
#include <math.h>

typedef unsigned int u32;
typedef unsigned long long u64;
typedef short s16x8 __attribute__((ext_vector_type(8)));
typedef float f32x4 __attribute__((ext_vector_type(4)));

#define HH 128
#define WW 128
#define NPIX (128*128)
#define NANCH (NPIX*6)
#define KPRE 6000
#define KPOST 300
#define SORT_CAP 16384
#define RW 96
#define NMS_T 0.7f

#define OUT_PROB 1500
#define OUT_BBOX (1500 + 98304)

/* ---------------- ws layout (bytes) ----------------
   [conv1 33.5M][Xth 33.5M|Xtl 33.5M][Wph 9.4M|Wpl 9.4M] = 119.5MB
   post-conv3 buffers alias offset 33.5MB. */
#define WS_CONV1 ((size_t)0)
#define WS_XTH   ((size_t)33554432)
#define WS_WPH   ((size_t)100663296)
#define WS_BOXES ((size_t)33554432)
#define WS_SCORE (WS_BOXES + 1572864)
#define WS_KEYS  (WS_SCORE + 393216)
#define WS_TB    (WS_KEYS + 131072)
#define WS_AREA  (WS_TB + 98304)
#define WS_SUP   (WS_AREA + 24576)
#define WS_HIST  (WS_SUP + 4718592)
#define WS_CTRL  (WS_HIST + 262144)
#define WS_KEEP  (WS_CTRL + 256)
#define WS_SKEYS (WS_KEEP + 1280)

__device__ __forceinline__ unsigned short f2bf(float x) {
    u32 b = __float_as_uint(x);
    u32 r = (b + 0x7FFFu + ((b >> 16) & 1u)) >> 16;
    return (unsigned short)r;
}

/* async global->LDS, 16B/lane: dest = wave-uniform base + lane*16 */
__device__ __forceinline__ void gl_lds16(const void* g, void* l) {
    __builtin_amdgcn_global_load_lds(
        (__attribute__((address_space(1))) const void*)g,
        (__attribute__((address_space(3))) void*)l,
        16, 0, 0);
}

/* ---------------- init (after conv3; aliases staging region) ---------------- */
__global__ void k_init(u32* __restrict__ hist, u32* __restrict__ ctrl,
                       int* __restrict__ keep, u64* __restrict__ keys) {
    int t = blockIdx.x * blockDim.x + threadIdx.x;
    if (t < 65536) hist[t] = 0u;
    if (t < 64)    ctrl[t] = 0u;
    if (t < 304)   keep[t] = -1;
    if (t < SORT_CAP) keys[t] = ~0ULL;
}

/* X prepass: in[c][pix] f32 -> Xth[pix][c], Xtl[pix][c] bf16 (transpose+split) */
__global__ __launch_bounds__(256) void k_xsplit(const float* __restrict__ in,
                                                unsigned short* __restrict__ xth) {
    unsigned short* xtl = xth + 16777216;
    __shared__ unsigned short Th[64][72];
    __shared__ unsigned short Tl[64][72];
    const int px0 = blockIdx.x * 64;   /* 256 */
    const int c0  = blockIdx.y * 64;   /* 16  */
    const int t = threadIdx.x;
    const int r = t >> 4;
    const int p4 = (t & 15) * 4;
#pragma unroll
    for (int i = 0; i < 4; ++i) {
        int cr = r + 16 * i;
        float4 v = *(const float4*)(in + (size_t)(c0 + cr) * NPIX + px0 + p4);
        float vv[4] = {v.x, v.y, v.z, v.w};
#pragma unroll
        for (int k = 0; k < 4; ++k) {
            unsigned short h = f2bf(vv[k]);
            float hf = __uint_as_float((u32)h << 16);
            unsigned short l = f2bf(vv[k] - hf);
            Th[p4 + k][cr] = h;
            Tl[p4 + k][cr] = l;
        }
    }
    __syncthreads();
    const int p = t >> 2, q = t & 3;
    unsigned short* dh = xth + (size_t)(px0 + p) * 1024 + c0 + q * 16;
    unsigned short* dl = xtl + (size_t)(px0 + p) * 1024 + c0 + q * 16;
    *(uint4*)dh       = *(const uint4*)&Th[p][q * 16];
    *(uint4*)(dh + 8) = *(const uint4*)&Th[p][q * 16 + 8];
    *(uint4*)dl       = *(const uint4*)&Tl[p][q * 16];
    *(uint4*)(dl + 8) = *(const uint4*)&Tl[p][q * 16 + 8];
}

/* W prepass: w[oc][c*9+tap] -> Wph[tap][oc][c], Wpl[...] bf16; + zero-stash */
__global__ __launch_bounds__(256) void k_wpack(const float* __restrict__ w,
                                               unsigned short* __restrict__ wph,
                                               float* __restrict__ zstash) {
    if (blockIdx.x == 0 && threadIdx.x < 128) zstash[threadIdx.x] = 0.f;
    int id = blockIdx.x * 256 + threadIdx.x;     /* 524288 = oc*1024 + c */
    int oc = id >> 10, c = id & 1023;
    const float* src = w + (size_t)oc * 9216 + c * 9;
#pragma unroll
    for (int tap = 0; tap < 9; ++tap) {
        float x = src[tap];
        unsigned short h = f2bf(x);
        unsigned short l = f2bf(x - __uint_as_float((u32)h << 16));
        wph[(size_t)tap * 524288 + id] = h;
        wph[4718592 + (size_t)tap * 524288 + id] = l;
    }
}

/* conv3 via MFMA, tap-major. Block = 128oc x 128px (one image row y), 4 waves.
   Wave = 64oc x 64px = 4x4 tiles of 16x16. 288 stages = 9 taps x 32 channels.
   Per stage per wave: 8 global_load_lds (zero VGPR staging, double-buffered),
   16 ds_read_b128, 48 MFMA -> 48 FLOP/LDS-byte (MFMA-bound).
   LDS per buffer: X [pl][128px][32c] 16KB + W [pl][128oc][32c] 16KB; x2 = 64KB.
   Granule swizzle g^( (row>>1)&3 ) on DMA source -> 2-way LDS reads (free).
   Edge taps (y=0/127) and x-halo fed from zstash: uniform, branch-free. */
__global__ __launch_bounds__(256, 2) void k_conv3m(const unsigned short* __restrict__ xt,
                                                   const unsigned short* __restrict__ wp,
                                                   const float* __restrict__ bias,
                                                   const unsigned short* __restrict__ zst,
                                                   float* __restrict__ out) {
    const int ocg = blockIdx.x;          /* 0..3 -> const per XCD */
    const int y   = blockIdx.y;          /* 0..127 */
    const int oc0 = ocg * 128;
    const int tid = threadIdx.x;
    const int lane = tid & 63;
    const int w    = tid >> 6;
    const int l15  = lane & 15;
    const int quad = lane >> 4;
    const int hoc  = w >> 1, hpx = w & 1;

    __shared__ __align__(16) unsigned short Lds[32768];   /* 64 KB */

    /* DMA slot geometry (per wave: 4 X slots + 4 W slots) */
    const int lg  = lane & 3;            /* LDS granule this lane fills  */
    const int lr  = lane >> 2;           /* row-within-16 this lane fills */

    const unsigned short* xsrc[4];
    int xstep[4];
    const unsigned short* wsrc[4];

    /* W sources: tap-linear, never redirected */
    int wp_pl[4], wp_ocr[4], wp_gs[4];
#pragma unroll
    for (int j = 0; j < 4; ++j) {
        int i = w + 4 * j;
        wp_pl[j]  = i >> 3;
        wp_ocr[j] = (i & 7) * 16 + lr;
        wp_gs[j]  = lg ^ ((wp_ocr[j] >> 1) & 3);
    }
    int xp_pl[4], xp_p[4], xp_gs[4];
#pragma unroll
    for (int j = 0; j < 4; ++j) {
        int i = w + 4 * j;
        xp_pl[j] = i >> 3;
        xp_p[j]  = (i & 7) * 16 + lr;
        xp_gs[j] = lg ^ ((xp_p[j] >> 1) & 3);
    }

    auto set_tap = [&](int tap) {
        int dy = tap / 3, dx = tap - dy * 3;
        int yy = y + dy - 1;
        bool yok = (yy >= 0) && (yy < HH);
#pragma unroll
        for (int j = 0; j < 4; ++j) {
            int x = dx - 1 + xp_p[j];
            bool ok = yok && (x >= 0) && (x < WW);
            xsrc[j] = ok ? xt + (size_t)xp_pl[j] * 16777216
                              + (size_t)(yy * WW + x) * 1024 + xp_gs[j] * 8
                         : zst + lg * 8;
            xstep[j] = ok ? 32 : 0;
        }
#pragma unroll
        for (int j = 0; j < 4; ++j)
            wsrc[j] = wp + (size_t)wp_pl[j] * 4718592 + (size_t)tap * 524288
                        + (size_t)(oc0 + wp_ocr[j]) * 1024 + wp_gs[j] * 8;
    };

    auto issue = [&](int sel) {
        const int bo = sel * 16384;
#pragma unroll
        for (int j = 0; j < 4; ++j) {
            gl_lds16(xsrc[j], &Lds[bo + (w + 4 * j) * 512]);
            xsrc[j] += xstep[j];
        }
#pragma unroll
        for (int j = 0; j < 4; ++j) {
            gl_lds16(wsrc[j], &Lds[bo + 8192 + (w + 4 * j) * 512]);
            wsrc[j] += 32;
        }
    };

    /* compute-side read bases: swizzle g identical for all og/nt (stride 16) */
    const int g  = quad ^ ((l15 >> 1) & 3);
    const int bB0 = (hpx * 64 + l15) * 32 + g * 8;
    const int bA0 = 8192 + (hoc * 64 + l15) * 32 + g * 8;

    f32x4 acc[4][4];
#pragma unroll
    for (int og = 0; og < 4; ++og)
#pragma unroll
        for (int nt = 0; nt < 4; ++nt) acc[og][nt] = (f32x4){0.f, 0.f, 0.f, 0.f};

    set_tap(0);
    issue(0);

    for (int s = 0; s < 288; ++s) {
        const int cur = s & 1;
        __syncthreads();        /* drains cur-buffer DMA (in flight one full
                                   stage) + all waves done with other buffer */
        if (s + 1 < 288) {
            int s1 = s + 1;
            if ((s1 & 31) == 0) set_tap(s1 >> 5);
            issue(s1 & 1);
        }

        const int bo = cur * 16384;
        s16x8 ah[4], al[4];
#pragma unroll
        for (int og = 0; og < 4; ++og) {
            ah[og] = *(const s16x8*)&Lds[bo + bA0 + og * 512];
            al[og] = *(const s16x8*)&Lds[bo + bA0 + 4096 + og * 512];
        }
#pragma unroll
        for (int nt = 0; nt < 4; ++nt) {
            const s16x8 bh = *(const s16x8*)&Lds[bo + bB0 + nt * 512];
            const s16x8 bl = *(const s16x8*)&Lds[bo + bB0 + 4096 + nt * 512];
#pragma unroll
            for (int og = 0; og < 4; ++og) {
                acc[og][nt] = __builtin_amdgcn_mfma_f32_16x16x32_bf16(ah[og], bh, acc[og][nt], 0, 0, 0);
                acc[og][nt] = __builtin_amdgcn_mfma_f32_16x16x32_bf16(ah[og], bl, acc[og][nt], 0, 0, 0);
                acc[og][nt] = __builtin_amdgcn_mfma_f32_16x16x32_bf16(al[og], bh, acc[og][nt], 0, 0, 0);
            }
        }
    }

    /* epilogue: D row(oc) = quad*4+reg, col(px) = l15 */
#pragma unroll
    for (int og = 0; og < 4; ++og) {
#pragma unroll
        for (int nt = 0; nt < 4; ++nt) {
#pragma unroll
            for (int rg = 0; rg < 4; ++rg) {
                const int oc = oc0 + hoc * 64 + og * 16 + quad * 4 + rg;
                const int px = hpx * 64 + nt * 16 + l15;
                float v = acc[og][nt][rg] + bias[oc];
                out[(size_t)oc * NPIX + y * WW + px] = fmaxf(v, 0.f);
            }
        }
    }
}

/* ---------------- fused 1x1 convs + pair softmax ---------------- */
__global__ __launch_bounds__(256) void k_conv1(const float* __restrict__ conv1,
                                               const float* __restrict__ wcls,
                                               const float* __restrict__ bcls,
                                               const float* __restrict__ wbox,
                                               const float* __restrict__ bboxb,
                                               float* __restrict__ out) {
    const int tid = threadIdx.x;
    const int og = tid >> 4, pg = tid & 15;
    const int px0 = blockIdx.x * 64;
    __shared__ __align__(16) float Wl[32][32];
    __shared__ __align__(16) float Xl[32][64];
    __shared__ float Sc[6][64];

    float a0[4] = {0, 0, 0, 0}, a1[4] = {0, 0, 0, 0};

    for (int cc = 0; cc < 16; ++cc) {
        {
            int u = tid;
            int row = (u * 4) >> 5;
            int col = (u * 4) & 31;
            float4 v;
            if (row < 6)       v = *(const float4*)(wcls + row * 512 + cc * 32 + col);
            else if (row < 30) v = *(const float4*)(wbox + (row - 6) * 512 + cc * 32 + col);
            else               v = make_float4(0.f, 0.f, 0.f, 0.f);
            *(float4*)&Wl[row][col] = v;
        }
        for (int u = tid; u < 512; u += 256) {
            int row = (u * 4) >> 6, col = (u * 4) & 63;
            *(float4*)&Xl[row][col] =
                *(const float4*)(conv1 + (size_t)(cc * 32 + row) * NPIX + px0 + col);
        }
        __syncthreads();
#pragma unroll
        for (int cp = 0; cp < 32; ++cp) {
            const float4 x = *(const float4*)&Xl[cp][pg * 4];
            const float w0 = Wl[og][cp];
            const float w1 = Wl[og + 16][cp];
            a0[0] = fmaf(w0, x.x, a0[0]); a0[1] = fmaf(w0, x.y, a0[1]);
            a0[2] = fmaf(w0, x.z, a0[2]); a0[3] = fmaf(w0, x.w, a0[3]);
            a1[0] = fmaf(w1, x.x, a1[0]); a1[1] = fmaf(w1, x.y, a1[1]);
            a1[2] = fmaf(w1, x.z, a1[2]); a1[3] = fmaf(w1, x.w, a1[3]);
        }
        __syncthreads();
    }
    const int pxb = px0 + pg * 4;
    if (og < 6) {
        const float bc = bcls[og];
#pragma unroll
        for (int kk = 0; kk < 4; ++kk) Sc[og][pg * 4 + kk] = a0[kk] + bc;
    } else {
        const float bb = bboxb[og - 6];
#pragma unroll
        for (int kk = 0; kk < 4; ++kk)
            out[OUT_BBOX + (size_t)(og - 6) * NPIX + pxb + kk] = a0[kk] + bb;
    }
    if (og + 16 < 30) {
        const float bb = bboxb[og + 10];
#pragma unroll
        for (int kk = 0; kk < 4; ++kk)
            out[OUT_BBOX + (size_t)(og + 10) * NPIX + pxb + kk] = a1[kk] + bb;
    }
    __syncthreads();
    if (og < 6) {
        const int pa = og < 3 ? og + 3 : og - 3;
#pragma unroll
        for (int kk = 0; kk < 4; ++kk) {
            const float s = Sc[og][pg * 4 + kk], sp = Sc[pa][pg * 4 + kk];
            out[OUT_PROB + (size_t)og * NPIX + pxb + kk] = 1.0f / (1.0f + expf(sp - s));
        }
    }
}

/* ---------------- anchor decode + clip ---------------- */
__global__ void k_decode(const float* __restrict__ out, const float* __restrict__ meta,
                         float4* __restrict__ boxes, float* __restrict__ scores) {
#pragma clang fp contract(off)
    int t = blockIdx.x * blockDim.x + threadIdx.x;
    if (t >= NANCH) return;
    int a = t >> 14;
    int pix = t & 16383;
    int yc = pix >> 7, xc = pix & 127;
    int n = pix * 6 + a;
    float sc = out[OUT_PROB + (size_t)a * NPIX + pix];
    float d0 = out[OUT_BBOX + (size_t)(a * 4 + 0) * NPIX + pix];
    float d1 = out[OUT_BBOX + (size_t)(a * 4 + 1) * NPIX + pix];
    float d2 = out[OUT_BBOX + (size_t)(a * 4 + 2) * NPIX + pix];
    float d3 = out[OUT_BBOX + (size_t)(a * 4 + 3) * NPIX + pix];
    const float dims = (float)(16 << a);
    const float cxa = (xc + 0.5f) * 16.f;
    const float cya = (yc + 0.5f) * 16.f;
    float pcx = d0 * dims + cxa;
    float pcy = d1 * dims + cya;
    float pw  = expf(d2) * dims;
    float ph  = expf(d3) * dims;
    float imh = meta[0], imw = meta[1];
    float x1 = fminf(fmaxf(pcx - 0.5f * pw, 0.f), imw);
    float y1 = fminf(fmaxf(pcy - 0.5f * ph, 0.f), imh);
    float x2 = fminf(fmaxf(pcx + 0.5f * pw, 0.f), imw);
    float y2 = fminf(fmaxf(pcy + 0.5f * ph, 0.f), imh);
    boxes[n] = make_float4(x1, y1, x2, y2);
    scores[n] = sc;
}

__global__ void k_hist(const float* __restrict__ scores, u32* __restrict__ hist) {
    int t = blockIdx.x * blockDim.x + threadIdx.x;
    if (t >= NANCH) return;
    u32 b = __float_as_uint(scores[t]) >> 16;
    atomicAdd(&hist[b], 1u);
}

__global__ void k_select(const u32* __restrict__ hist, u32* __restrict__ ctrl) {
    __shared__ u32 S[256];
    __shared__ u32 U[256];
    const int tid = threadIdx.x;
    u32 s = 0;
    for (int i = 0; i < 256; ++i) s += hist[tid * 256 + i];
    S[tid] = s;
    __syncthreads();
    if (tid == 0) {
        u32 acc = 0;
        for (int t2 = 255; t2 >= 0; --t2) { U[t2] = acc; acc += S[t2]; }
    }
    __syncthreads();
    if (U[tid] < KPRE && U[tid] + S[tid] >= KPRE) {
        u32 acc = U[tid];
        for (int b = tid * 256 + 255; b >= tid * 256; --b) {
            u32 h = hist[b];
            if (acc + h >= KPRE) { ctrl[1] = (u32)b; ctrl[2] = acc; break; }
            acc += h;
        }
    }
}

__global__ void k_compact(const float* __restrict__ scores, u32* __restrict__ ctrl,
                          u64* __restrict__ keys) {
    int t = blockIdx.x * blockDim.x + threadIdx.x;
    if (t >= NANCH) return;
    u32 bits = __float_as_uint(scores[t]);
    if ((bits >> 16) >= ctrl[1]) {
        u32 pos = atomicAdd(&ctrl[0], 1u);
        if (pos < SORT_CAP) keys[pos] = ((u64)(~bits) << 32) | (u32)t;
    }
}

__global__ __launch_bounds__(1024) void k_sort_local(u64* __restrict__ keys) {
    __shared__ u64 lds[8192];
    const int tid = threadIdx.x;
    u64* g = keys + blockIdx.x * 8192;
    for (int u = tid; u < 8192; u += 1024) lds[u] = g[u];
    __syncthreads();
    for (int k = 2; k <= 8192; k <<= 1) {
        for (int j = k >> 1; j > 0; j >>= 1) {
            for (int u = tid; u < 4096; u += 1024) {
                int i = ((u & ~(j - 1)) << 1) | (u & (j - 1));
                int l = i | j;
                bool up = (i & k) == 0;
                u64 x = lds[i], y2 = lds[l];
                if ((x > y2) == up) { lds[i] = y2; lds[l] = x; }
            }
            __syncthreads();
        }
    }
    for (int u = tid; u < 8192; u += 1024) g[u] = lds[u];
}

__global__ void k_merge(const u64* __restrict__ keys, u64* __restrict__ skeys) {
    int i = blockIdx.x * blockDim.x + threadIdx.x;
    if (i >= KPRE) return;
    const u64* A = keys;
    const u64* B = keys + 8192;
    int lo = i > 8192 ? i - 8192 : 0;
    int hi = i < 8192 ? i : 8192;
    while (lo < hi) {
        int a = (lo + hi) >> 1;
        if (A[a] < B[i - a - 1]) lo = a + 1; else hi = a;
    }
    int a = lo, b = i - lo;
    u64 va = (a < 8192) ? A[a] : ~0ULL;
    u64 vb = (b < 8192) ? B[b] : ~0ULL;
    skeys[i] = va < vb ? va : vb;
}

__global__ void k_gather(const u64* __restrict__ skeys, const float4* __restrict__ boxes,
                         float4* __restrict__ tb, float* __restrict__ areas) {
#pragma clang fp contract(off)
    int i = blockIdx.x * blockDim.x + threadIdx.x;
    if (i >= KPRE) return;
    u32 n = (u32)(skeys[i] & 0xFFFFFFFFULL);
    float4 b = boxes[n];
    tb[i] = b;
    areas[i] = fmaxf(b.z - b.x, 0.f) * fmaxf(b.w - b.y, 0.f);
}

__global__ __launch_bounds__(256) void k_bitmap(const float4* __restrict__ tb,
                                                const float* __restrict__ areas,
                                                u64* __restrict__ suppr) {
#pragma clang fp contract(off)
    const int i = blockIdx.x;
    const int lane = threadIdx.x & 63;
    const int wv = threadIdx.x >> 6;
    const float4 bi = tb[i];
    const float ai = areas[i];
    for (int Wd = wv; Wd < RW; Wd += 4) {
        int j = Wd * 64 + lane;
        bool sup = false;
        if (j < KPRE) {
            float4 bj = tb[j];
            float iw = fmaxf(fminf(bi.z, bj.z) - fmaxf(bi.x, bj.x), 0.f);
            float ih = fmaxf(fminf(bi.w, bj.w) - fmaxf(bi.y, bj.y), 0.f);
            float inter = iw * ih;
            float denom = ((areas[j] + ai) - inter) + 1e-9f;
            sup = (inter / denom) > NMS_T;
        }
        u64 m = __ballot(sup);
        if (lane == 0) suppr[(size_t)i * RW + Wd] = m;
    }
}

__global__ void k_scan(const u64* __restrict__ suppr, int* __restrict__ keep) {
    const int lane = threadIdx.x;
    u64 a0 = (lane < 93) ? ~0ULL : (lane == 93 ? ((1ULL << 48) - 1) : 0ULL);
    const int w1 = lane + 64;
    u64 a1 = (w1 < 93) ? ~0ULL : (w1 == 93 ? ((1ULL << 48) - 1) : 0ULL);
    int kept = 0;
    int i = 0;
    while (kept < KPOST) {
        int wi = i >> 6;
        if (wi >= 94) break;
        u64 wvv = (wi < 64) ? __shfl(a0, wi) : __shfl(a1, wi - 64);
        wvv &= (~0ULL) << (i & 63);
        if (wvv == 0ULL) { i = (wi + 1) << 6; continue; }
        int b = __ffsll((long long)wvv) - 1;
        i = (wi << 6) + b;
        if (lane == 0) keep[kept] = i;
        kept++;
        const u64* row = suppr + (size_t)i * RW;
        u64 s0 = row[lane];
        u64 s1 = (lane + 64 < RW) ? row[lane + 64] : 0ULL;
        a0 &= ~s0;
        a1 &= ~s1;
        i++;
    }
}

__global__ void k_rois(const int* __restrict__ keep, const float4* __restrict__ tb,
                       float* __restrict__ out) {
    int r = blockIdx.x * blockDim.x + threadIdx.x;
    if (r >= KPOST) return;
    int k = keep[r];
    float4 b = make_float4(0.f, 0.f, 0.f, 0.f);
    if (k >= 0) b = tb[k];
    out[r * 5 + 0] = 0.f;
    out[r * 5 + 1] = b.x;
    out[r * 5 + 2] = b.y;
    out[r * 5 + 3] = b.z;
    out[r * 5 + 4] = b.w;
}

extern "C" void kernel_launch(void* const* d_in, const int* in_sizes, int n_in,
                              void* d_out, int out_size, void* d_ws, size_t ws_size,
                              hipStream_t stream) {
    (void)in_sizes; (void)n_in; (void)out_size; (void)ws_size;
    const float* x     = (const float*)d_in[0];
    const float* meta  = (const float*)d_in[1];
    const float* wc3   = (const float*)d_in[3];
    const float* bc3   = (const float*)d_in[4];
    const float* wcls  = (const float*)d_in[5];
    const float* bcls  = (const float*)d_in[6];
    const float* wbox  = (const float*)d_in[7];
    const float* bboxb = (const float*)d_in[8];
    float* out = (float*)d_out;
    char* ws = (char*)d_ws;

    float*  conv1  = (float*)(ws + WS_CONV1);
    float4* boxes  = (float4*)(ws + WS_BOXES);
    float*  scores = (float*)(ws + WS_SCORE);
    u64*    keys   = (u64*)(ws + WS_KEYS);
    float4* tb     = (float4*)(ws + WS_TB);
    float*  areas  = (float*)(ws + WS_AREA);
    u64*    suppr  = (u64*)(ws + WS_SUP);
    u32*    hist   = (u32*)(ws + WS_HIST);
    u32*    ctrl   = (u32*)(ws + WS_CTRL);
    int*    keep   = (int*)(ws + WS_KEEP);
    u64*    skeys  = (u64*)(ws + WS_SKEYS);

    float* zstash = out;   /* 512B zeros; rewritten by k_rois at the end */

    unsigned short* xth = (unsigned short*)(ws + WS_XTH);
    unsigned short* wph = (unsigned short*)(ws + WS_WPH);
    k_xsplit<<<dim3(256, 16), 256, 0, stream>>>(x, xth);
    k_wpack<<<2048, 256, 0, stream>>>(wc3, wph, zstash);
    k_conv3m<<<dim3(4, 128), 256, 0, stream>>>(xth, wph, bc3,
                                               (const unsigned short*)zstash, conv1);

    k_init<<<256, 256, 0, stream>>>(hist, ctrl, keep, keys);
    k_conv1<<<256, 256, 0, stream>>>(conv1, wcls, bcls, wbox, bboxb, out);
    k_decode<<<384, 256, 0, stream>>>(out, meta, boxes, scores);
    k_hist<<<384, 256, 0, stream>>>(scores, hist);
    k_select<<<1, 256, 0, stream>>>(hist, ctrl);
    k_compact<<<384, 256, 0, stream>>>(scores, ctrl, keys);
    k_sort_local<<<2, 1024, 0, stream>>>(keys);
    k_merge<<<24, 256, 0, stream>>>(keys, skeys);
    k_gather<<<24, 256, 0, stream>>>(skeys, boxes, tb, areas);
    k_bitmap<<<6000, 256, 0, stream>>>(tb, areas, suppr);
    k_scan<<<1, 64, 0, stream>>>(suppr, keep);
    k_rois<<<2, 256, 0, stream>>>(keep, tb, out);
}